// Round 2
// baseline (1505.829 us; speedup 1.0000x reference)
//
#include <hip/hip_runtime.h>
#include <hip/hip_bf16.h>

#define D_MODEL 512
#define D_INNER 1024
#define D_STATE 16
#define DT_RANK 32
#define BB 2
#define LL 2048
#define RR (BB*LL)   // 4096

// ---------------- K1: m = silu(diff) @ ada_w.T + ada_b  (m: [2][1024] fp32) ------------
__global__ void k_ada(const float* __restrict__ diff,
                      const float* __restrict__ aw,
                      const float* __restrict__ ab,
                      float* __restrict__ m) {
  __shared__ float sd[D_MODEL];
  const int b = blockIdx.y;
  const int t = threadIdx.x;
  for (int k = t; k < D_MODEL; k += 256) {
    float v = diff[b*D_MODEL + k];
    sd[k] = v / (1.f + __expf(-v));
  }
  __syncthreads();
  const int j = blockIdx.x*256 + t;  // 0..1023
  const float4* wr = reinterpret_cast<const float4*>(aw + (size_t)j*D_MODEL);
  float acc = ab[j];
  #pragma unroll 4
  for (int k4 = 0; k4 < D_MODEL/4; ++k4) {
    float4 wv = wr[k4];
    acc += sd[4*k4]*wv.x + sd[4*k4+1]*wv.y + sd[4*k4+2]*wv.z + sd[4*k4+3]*wv.w;
  }
  m[b*(2*D_MODEL) + j] = acc;
}

// ---------------- K2: xz = (q*(1+scale)+shift) @ in_proj_w.T   [4096][2048] fp32 -------
__global__ void k_inproj(const float* __restrict__ q,
                         const float* __restrict__ w,   // [2048][512]
                         const float* __restrict__ m,   // [2][1024]
                         float* __restrict__ xz) {      // [4096][2048]
  __shared__ float As[16][68];
  __shared__ float Bs[16][68];
  const int tx = threadIdx.x, ty = threadIdx.y;
  const int t = ty*16 + tx;
  const int row0 = blockIdx.y*64;
  const int col0 = blockIdx.x*64;
  const float* mb = m + (row0 >> 11)*(2*D_MODEL);
  float acc[4][4] = {};
  for (int k0 = 0; k0 < D_MODEL; k0 += 16) {
    #pragma unroll
    for (int i = 0; i < 4; ++i) {
      int e = t + i*256;
      int kk = e & 15, rr = e >> 4;
      float sc = mb[k0+kk], sh = mb[D_MODEL + k0+kk];
      As[kk][rr] = q[(size_t)(row0+rr)*D_MODEL + k0+kk] * (1.f + sc) + sh;
      Bs[kk][rr] = w[(size_t)(col0+rr)*D_MODEL + k0+kk];
    }
    __syncthreads();
    #pragma unroll
    for (int kk = 0; kk < 16; ++kk) {
      float4 av = *reinterpret_cast<const float4*>(&As[kk][ty*4]);
      float4 bv = *reinterpret_cast<const float4*>(&Bs[kk][tx*4]);
      float a[4] = {av.x, av.y, av.z, av.w};
      float bq[4] = {bv.x, bv.y, bv.z, bv.w};
      #pragma unroll
      for (int i = 0; i < 4; ++i)
        #pragma unroll
        for (int j = 0; j < 4; ++j)
          acc[i][j] += a[i]*bq[j];
    }
    __syncthreads();
  }
  #pragma unroll
  for (int i = 0; i < 4; ++i) {
    float4 v = make_float4(acc[i][0], acc[i][1], acc[i][2], acc[i][3]);
    *reinterpret_cast<float4*>(&xz[(size_t)(row0+ty*4+i)*(2*D_INNER) + col0 + tx*4]) = v;
  }
}

// ---------------- K3: xc = silu(causal_conv4(xm) + conv_b)   [4096][1024] fp32 ----------
__global__ void k_conv(const float* __restrict__ xz,
                       const float* __restrict__ cw,  // [1024][4]
                       const float* __restrict__ cb,
                       float* __restrict__ xc) {
  const int gid = blockIdx.x*256 + threadIdx.x;   // over 4096*1024
  const int d = gid & (D_INNER-1);
  const int r = gid >> 10;
  const int l = r & (LL-1);
  float4 cv = *reinterpret_cast<const float4*>(cw + (size_t)d*4);
  float wv[4] = {cv.x, cv.y, cv.z, cv.w};
  float acc = cb[d];
  #pragma unroll
  for (int k = 0; k < 4; ++k) {
    int ls = l + k - 3;
    if (ls >= 0) acc += xz[(size_t)(r + k - 3)*(2*D_INNER) + d] * wv[k];
  }
  xc[gid] = acc / (1.f + __expf(-acc));
}

// ---------------- K4: xdb = xc @ x_proj_w.T   [4096][64] fp32 ---------------------------
__global__ void k_xproj(const float* __restrict__ xc,
                        const float* __restrict__ xw,  // [64][1024]
                        float* __restrict__ xdb) {
  const int gid = blockIdx.x*256 + threadIdx.x;   // 4096*64
  const int j = gid & 63, r = gid >> 6;
  const float4* xr = reinterpret_cast<const float4*>(xc + (size_t)r*D_INNER);
  const float4* wr = reinterpret_cast<const float4*>(xw + (size_t)j*D_INNER);
  float acc = 0.f;
  #pragma unroll 4
  for (int i = 0; i < D_INNER/4; ++i) {
    float4 xv = xr[i];
    float4 wv = wr[i];
    acc += xv.x*wv.x + xv.y*wv.y + xv.z*wv.z + xv.w*wv.w;
  }
  xdb[gid] = acc;
}

// ---------------- K5: delta = softplus(dt @ dt_proj_w.T + dt_proj_b)  [4096][1024] ------
__global__ void k_delta(const float* __restrict__ xdb,
                        const float* __restrict__ dw,  // [1024][32]
                        const float* __restrict__ db,
                        float* __restrict__ delta) {
  const int gid = blockIdx.x*256 + threadIdx.x;   // 4096*1024
  const int d = gid & (D_INNER-1), r = gid >> 10;
  const float4* xr = reinterpret_cast<const float4*>(xdb + (size_t)r*64);
  const float4* wr = reinterpret_cast<const float4*>(dw + (size_t)d*DT_RANK);
  float acc = db[d];
  #pragma unroll
  for (int i = 0; i < DT_RANK/4; ++i) {
    float4 xv = xr[i];
    float4 wv = wr[i];
    acc += xv.x*wv.x + xv.y*wv.y + xv.z*wv.z + xv.w*wv.w;
  }
  delta[gid] = (acc > 20.f) ? acc : __logf(1.f + __expf(acc));
}

// ---------------- K6: sequential selective scan -> y  [4096][1024] fp32 -----------------
__global__ void __launch_bounds__(64) k_scan(
    const float* __restrict__ delta,   // [4096][1024]
    const float* __restrict__ xc,      // [4096][1024]
    const float* __restrict__ xdb,     // [4096][64] (B at +32, C at +48)
    const float* __restrict__ alog,    // [1024][16]
    float* __restrict__ y) {
  const int d = blockIdx.x*64 + threadIdx.x;
  const int b = blockIdx.y;
  float A[D_STATE], h[D_STATE];
  #pragma unroll
  for (int n = 0; n < D_STATE; ++n) {
    A[n] = -__expf(alog[(size_t)d*D_STATE + n]);
    h[n] = 0.f;
  }
  const size_t base = (size_t)b*LL*D_INNER + d;
  const float* xrow = xdb + (size_t)b*LL*64;
  for (int t = 0; t < LL; ++t) {
    float dlt = delta[base + (size_t)t*D_INNER];
    float xv  = xc[base + (size_t)t*D_INNER];
    float dx = dlt * xv;
    const float4* bc = reinterpret_cast<const float4*>(xrow + t*64 + 32);
    float Bv[16], Cv[16];
    #pragma unroll
    for (int i = 0; i < 4; ++i) {
      float4 bq = bc[i], cq = bc[4+i];
      Bv[4*i+0]=bq.x; Bv[4*i+1]=bq.y; Bv[4*i+2]=bq.z; Bv[4*i+3]=bq.w;
      Cv[4*i+0]=cq.x; Cv[4*i+1]=cq.y; Cv[4*i+2]=cq.z; Cv[4*i+3]=cq.w;
    }
    float acc = 0.f;
    #pragma unroll
    for (int n = 0; n < D_STATE; ++n) {
      h[n] = __expf(dlt*A[n])*h[n] + dx*Bv[n];
      acc += h[n]*Cv[n];
    }
    y[base + (size_t)t*D_INNER] = acc;
  }
}

// ---------------- K7: y2 = (y + xc*D) * silu(z) -----------------------------------------
__global__ void k_gate(const float* __restrict__ y,
                       const float* __restrict__ xc,
                       const float* __restrict__ xz,
                       const float* __restrict__ Dp,
                       float* __restrict__ y2) {
  const int gid = blockIdx.x*256 + threadIdx.x;
  const int d = gid & (D_INNER-1), r = gid >> 10;
  float z = xz[(size_t)r*(2*D_INNER) + D_INNER + d];
  float sz = z / (1.f + __expf(-z));
  y2[gid] = (y[gid] + xc[gid]*Dp[d]) * sz;
}

// ---------------- K8: attn = y2 @ out_proj_w.T   [4096][512] fp32 -----------------------
__global__ void k_outproj(const float* __restrict__ y2,   // [4096][1024]
                          const float* __restrict__ w,    // [512][1024]
                          float* __restrict__ attn) {     // [4096][512]
  __shared__ float As[16][68];
  __shared__ float Bs[16][68];
  const int tx = threadIdx.x, ty = threadIdx.y;
  const int t = ty*16 + tx;
  const int row0 = blockIdx.y*64;
  const int col0 = blockIdx.x*64;
  float acc[4][4] = {};
  for (int k0 = 0; k0 < D_INNER; k0 += 16) {
    #pragma unroll
    for (int i = 0; i < 4; ++i) {
      int e = t + i*256;
      int kk = e & 15, rr = e >> 4;
      As[kk][rr] = y2[(size_t)(row0+rr)*D_INNER + k0+kk];
      Bs[kk][rr] = w[(size_t)(col0+rr)*D_INNER + k0+kk];
    }
    __syncthreads();
    #pragma unroll
    for (int kk = 0; kk < 16; ++kk) {
      float4 av = *reinterpret_cast<const float4*>(&As[kk][ty*4]);
      float4 bv = *reinterpret_cast<const float4*>(&Bs[kk][tx*4]);
      float a[4] = {av.x, av.y, av.z, av.w};
      float bq[4] = {bv.x, bv.y, bv.z, bv.w};
      #pragma unroll
      for (int i = 0; i < 4; ++i)
        #pragma unroll
        for (int j = 0; j < 4; ++j)
          acc[i][j] += a[i]*bq[j];
    }
    __syncthreads();
  }
  #pragma unroll
  for (int i = 0; i < 4; ++i) {
    float4 v = make_float4(acc[i][0], acc[i][1], acc[i][2], acc[i][3]);
    *reinterpret_cast<float4*>(&attn[(size_t)(row0+ty*4+i)*D_MODEL + col0 + tx*4]) = v;
  }
}

// ---------------- K9: out = LN(q + attn) * g + b  -> fp32 -------------------------------
__global__ void k_ln(const float* __restrict__ attn,
                     const float* __restrict__ q,
                     const float* __restrict__ g,
                     const float* __restrict__ bb,
                     float* __restrict__ out) {
  const int r = blockIdx.x;
  const int t = threadIdx.x;
  float v0 = attn[(size_t)r*D_MODEL + t]       + q[(size_t)r*D_MODEL + t];
  float v1 = attn[(size_t)r*D_MODEL + 256 + t] + q[(size_t)r*D_MODEL + 256 + t];
  float s = v0 + v1, sq = v0*v0 + v1*v1;
  #pragma unroll
  for (int off = 32; off; off >>= 1) {
    s  += __shfl_xor(s, off);
    sq += __shfl_xor(sq, off);
  }
  __shared__ float ss[4], qq[4], stats[2];
  const int wid = t >> 6, lane = t & 63;
  if (lane == 0) { ss[wid] = s; qq[wid] = sq; }
  __syncthreads();
  if (t == 0) {
    float S = ss[0]+ss[1]+ss[2]+ss[3];
    float Q = qq[0]+qq[1]+qq[2]+qq[3];
    float mu = S * (1.f/D_MODEL);
    float var = Q * (1.f/D_MODEL) - mu*mu;
    stats[0] = mu; stats[1] = rsqrtf(var + 1e-5f);
  }
  __syncthreads();
  float mu = stats[0], rs = stats[1];
  out[(size_t)r*D_MODEL + t]       = (v0-mu)*rs*g[t]     + bb[t];
  out[(size_t)r*D_MODEL + 256 + t] = (v1-mu)*rs*g[256+t] + bb[256+t];
}

extern "C" void kernel_launch(void* const* d_in, const int* in_sizes, int n_in,
                              void* d_out, int out_size, void* d_ws, size_t ws_size,
                              hipStream_t stream) {
  (void)in_sizes; (void)n_in; (void)out_size; (void)ws_size;
  const float* q    = (const float*)d_in[0];
  // d_in[1] (value) unused by reference
  const float* diff = (const float*)d_in[2];
  const float* aw   = (const float*)d_in[3];
  const float* ab   = (const float*)d_in[4];
  const float* inw  = (const float*)d_in[5];
  const float* cw   = (const float*)d_in[6];
  const float* cb   = (const float*)d_in[7];
  const float* xw   = (const float*)d_in[8];
  const float* dtw  = (const float*)d_in[9];
  const float* dtb  = (const float*)d_in[10];
  const float* alog = (const float*)d_in[11];
  const float* Dp   = (const float*)d_in[12];
  const float* outw = (const float*)d_in[13];
  const float* lng  = (const float*)d_in[14];
  const float* lnb  = (const float*)d_in[15];
  float* out = (float*)d_out;

  float* ws = (float*)d_ws;
  // workspace layout (floats) — with reuse: total 21,235,712 floats (~85 MB)
  float* m     = ws;                               // 2048
  float* xz    = ws + 2048;                        // 4096*2048
  float* xc    = xz + (size_t)RR*2*D_INNER;        // 4096*1024
  float* xdb   = xc + (size_t)RR*D_INNER;          // 4096*64
  float* delta = xdb + (size_t)RR*64;              // 4096*1024
  float* yv    = delta + (size_t)RR*D_INNER;       // 4096*1024
  float* y2    = delta;                            // reuse (delta dead after k_scan)
  float* attn  = yv;                               // reuse (y dead after k_gate)

  k_ada<<<dim3(4,2), 256, 0, stream>>>(diff, aw, ab, m);
  k_inproj<<<dim3((2*D_INNER)/64, RR/64), dim3(16,16), 0, stream>>>(q, inw, m, xz);
  k_conv<<<(RR*D_INNER)/256, 256, 0, stream>>>(xz, cw, cb, xc);
  k_xproj<<<(RR*64)/256, 256, 0, stream>>>(xc, xw, xdb);
  k_delta<<<(RR*D_INNER)/256, 256, 0, stream>>>(xdb, dtw, dtb, delta);
  k_scan<<<dim3(D_INNER/64, BB), 64, 0, stream>>>(delta, xc, xdb, alog, yv);
  k_gate<<<(RR*D_INNER)/256, 256, 0, stream>>>(yv, xc, xz, Dp, y2);
  k_outproj<<<dim3(D_MODEL/64, RR/64), dim3(16,16), 0, stream>>>(y2, outw, attn);
  k_ln<<<RR, 256, 0, stream>>>(attn, q, lng, lnb, out);
}

// Round 3
// 614.265 us; speedup vs baseline: 2.4514x; 2.4514x over previous
//
#include <hip/hip_runtime.h>
#include <hip/hip_bf16.h>

#define D_MODEL 512
#define D_INNER 1024
#define D_STATE 16
#define DT_RANK 32
#define BB 2
#define LL 2048
#define RR (BB*LL)   // 4096
#define NC 64        // chunks per sequence
#define CS 32        // chunk size (NC*CS == LL)

// ---------------- K1: m = silu(diff) @ ada_w.T + ada_b  (m: [2][1024] fp32) ------------
__global__ void k_ada(const float* __restrict__ diff,
                      const float* __restrict__ aw,
                      const float* __restrict__ ab,
                      float* __restrict__ m) {
  __shared__ float sd[D_MODEL];
  const int b = blockIdx.y;
  const int t = threadIdx.x;
  for (int k = t; k < D_MODEL; k += 256) {
    float v = diff[b*D_MODEL + k];
    sd[k] = v / (1.f + __expf(-v));
  }
  __syncthreads();
  const int j = blockIdx.x*256 + t;  // 0..1023
  const float4* wr = reinterpret_cast<const float4*>(aw + (size_t)j*D_MODEL);
  float acc = ab[j];
  #pragma unroll 4
  for (int k4 = 0; k4 < D_MODEL/4; ++k4) {
    float4 wv = wr[k4];
    acc += sd[4*k4]*wv.x + sd[4*k4+1]*wv.y + sd[4*k4+2]*wv.z + sd[4*k4+3]*wv.w;
  }
  m[b*(2*D_MODEL) + j] = acc;
}

// ---------------- K2: xz = (q*(1+scale)+shift) @ in_proj_w.T   [4096][2048] fp32 -------
__global__ void k_inproj(const float* __restrict__ q,
                         const float* __restrict__ w,   // [2048][512]
                         const float* __restrict__ m,   // [2][1024]
                         float* __restrict__ xz) {      // [4096][2048]
  __shared__ float As[16][68];
  __shared__ float Bs[16][68];
  const int tx = threadIdx.x, ty = threadIdx.y;
  const int t = ty*16 + tx;
  const int row0 = blockIdx.y*64;
  const int col0 = blockIdx.x*64;
  const float* mb = m + (row0 >> 11)*(2*D_MODEL);
  float acc[4][4] = {};
  for (int k0 = 0; k0 < D_MODEL; k0 += 16) {
    #pragma unroll
    for (int i = 0; i < 4; ++i) {
      int e = t + i*256;
      int kk = e & 15, rr = e >> 4;
      float sc = mb[k0+kk], sh = mb[D_MODEL + k0+kk];
      As[kk][rr] = q[(size_t)(row0+rr)*D_MODEL + k0+kk] * (1.f + sc) + sh;
      Bs[kk][rr] = w[(size_t)(col0+rr)*D_MODEL + k0+kk];
    }
    __syncthreads();
    #pragma unroll
    for (int kk = 0; kk < 16; ++kk) {
      float4 av = *reinterpret_cast<const float4*>(&As[kk][ty*4]);
      float4 bv = *reinterpret_cast<const float4*>(&Bs[kk][tx*4]);
      float a[4] = {av.x, av.y, av.z, av.w};
      float bq[4] = {bv.x, bv.y, bv.z, bv.w};
      #pragma unroll
      for (int i = 0; i < 4; ++i)
        #pragma unroll
        for (int j = 0; j < 4; ++j)
          acc[i][j] += a[i]*bq[j];
    }
    __syncthreads();
  }
  #pragma unroll
  for (int i = 0; i < 4; ++i) {
    float4 v = make_float4(acc[i][0], acc[i][1], acc[i][2], acc[i][3]);
    *reinterpret_cast<float4*>(&xz[(size_t)(row0+ty*4+i)*(2*D_INNER) + col0 + tx*4]) = v;
  }
}

// ---------------- K3: xc = silu(causal_conv4(xm) + conv_b)   [4096][1024] fp32 ----------
__global__ void k_conv(const float* __restrict__ xz,
                       const float* __restrict__ cw,  // [1024][4]
                       const float* __restrict__ cb,
                       float* __restrict__ xc) {
  const int gid = blockIdx.x*256 + threadIdx.x;   // over 4096*1024
  const int d = gid & (D_INNER-1);
  const int r = gid >> 10;
  const int l = r & (LL-1);
  float4 cv = *reinterpret_cast<const float4*>(cw + (size_t)d*4);
  float wv[4] = {cv.x, cv.y, cv.z, cv.w};
  float acc = cb[d];
  #pragma unroll
  for (int k = 0; k < 4; ++k) {
    int ls = l + k - 3;
    if (ls >= 0) acc += xz[(size_t)(r + k - 3)*(2*D_INNER) + d] * wv[k];
  }
  xc[gid] = acc / (1.f + __expf(-acc));
}

// ---------------- K4: xdb = xc @ x_proj_w.T   [4096][64] fp32 ---------------------------
__global__ void k_xproj(const float* __restrict__ xc,
                        const float* __restrict__ xw,  // [64][1024]
                        float* __restrict__ xdb) {
  const int gid = blockIdx.x*256 + threadIdx.x;   // 4096*64
  const int j = gid & 63, r = gid >> 6;
  const float4* xr = reinterpret_cast<const float4*>(xc + (size_t)r*D_INNER);
  const float4* wr = reinterpret_cast<const float4*>(xw + (size_t)j*D_INNER);
  float acc = 0.f;
  #pragma unroll 4
  for (int i = 0; i < D_INNER/4; ++i) {
    float4 xv = xr[i];
    float4 wv = wr[i];
    acc += xv.x*wv.x + xv.y*wv.y + xv.z*wv.z + xv.w*wv.w;
  }
  xdb[gid] = acc;
}

// ---------------- K5: delta = softplus(dt @ dt_proj_w.T + dt_proj_b)  [4096][1024] ------
__global__ void k_delta(const float* __restrict__ xdb,
                        const float* __restrict__ dw,  // [1024][32]
                        const float* __restrict__ db,
                        float* __restrict__ delta) {
  const int gid = blockIdx.x*256 + threadIdx.x;   // 4096*1024
  const int d = gid & (D_INNER-1), r = gid >> 10;
  const float4* xr = reinterpret_cast<const float4*>(xdb + (size_t)r*64);
  const float4* wr = reinterpret_cast<const float4*>(dw + (size_t)d*DT_RANK);
  float acc = db[d];
  #pragma unroll
  for (int i = 0; i < DT_RANK/4; ++i) {
    float4 xv = xr[i];
    float4 wv = wr[i];
    acc += xv.x*wv.x + xv.y*wv.y + xv.z*wv.z + xv.w*wv.w;
  }
  delta[gid] = (acc > 20.f) ? acc : __logf(1.f + __expf(acc));
}

// ---------------- K6a: chunk-local scan (h from 0) + decay product ----------------------
// state layout: [b][chunk][d][n]  idx = ((b*NC+c)*D_INNER + d)*16 + n
__global__ void __launch_bounds__(256) k_scan1(
    const float* __restrict__ delta,
    const float* __restrict__ xc,
    const float* __restrict__ xdb,
    const float* __restrict__ alog,
    float* __restrict__ aprod,
    float* __restrict__ hstate) {
  const int d = blockIdx.x*256 + threadIdx.x;
  const int c = blockIdx.y;
  const int b = blockIdx.z;
  float A[D_STATE], ap[D_STATE], h[D_STATE];
  #pragma unroll
  for (int n = 0; n < D_STATE; ++n) {
    A[n] = -__expf(alog[(size_t)d*D_STATE + n]);
    ap[n] = 1.f; h[n] = 0.f;
  }
  const size_t base = ((size_t)b*LL + (size_t)c*CS)*D_INNER + d;
  const float* xrow = xdb + ((size_t)b*LL + (size_t)c*CS)*64;
  for (int t = 0; t < CS; ++t) {
    float dlt = delta[base + (size_t)t*D_INNER];
    float xv  = xc[base + (size_t)t*D_INNER];
    float dx = dlt * xv;
    const float4* bptr = reinterpret_cast<const float4*>(xrow + t*64 + 32);
    float Bv[D_STATE];
    #pragma unroll
    for (int i = 0; i < 4; ++i) {
      float4 bq = bptr[i];
      Bv[4*i+0]=bq.x; Bv[4*i+1]=bq.y; Bv[4*i+2]=bq.z; Bv[4*i+3]=bq.w;
    }
    #pragma unroll
    for (int n = 0; n < D_STATE; ++n) {
      float e = __expf(dlt*A[n]);
      ap[n] *= e;
      h[n] = e*h[n] + dx*Bv[n];
    }
  }
  const size_t sidx = (((size_t)b*NC + c)*D_INNER + d)*16;
  #pragma unroll
  for (int i = 0; i < 4; ++i) {
    *reinterpret_cast<float4*>(aprod + sidx + 4*i) =
        make_float4(ap[4*i], ap[4*i+1], ap[4*i+2], ap[4*i+3]);
    *reinterpret_cast<float4*>(hstate + sidx + 4*i) =
        make_float4(h[4*i], h[4*i+1], h[4*i+2], h[4*i+3]);
  }
}

// ---------------- K6b: combine chunk states; hstate[c] becomes INCOMING state -----------
__global__ void k_scan2(const float* __restrict__ aprod,
                        float* __restrict__ hstate) {
  const int gid = blockIdx.x*256 + threadIdx.x;   // over BB*D_INNER*16 = 32768
  const int b = gid >> 14;
  const int dn = gid & 16383;
  float h = 0.f;
  for (int c = 0; c < NC; ++c) {
    const size_t idx = ((size_t)(b*NC + c))*D_INNER*16 + dn;
    float a  = aprod[idx];
    float hl = hstate[idx];
    hstate[idx] = h;       // incoming state for chunk c
    h = a*h + hl;          // outgoing
  }
}

// ---------------- K6c: re-scan seeded + fused gate; writes y2 into xz xm-half -----------
__global__ void __launch_bounds__(256) k_scan3(
    const float* __restrict__ delta,
    const float* __restrict__ xc,
    const float* __restrict__ xdb,
    const float* __restrict__ alog,
    const float* __restrict__ hstate,
    const float* __restrict__ Dp,
    float* xz) {                           // read z at +D_INNER, write y2 at +0 (stride 2*D_INNER)
  const int d = blockIdx.x*256 + threadIdx.x;
  const int c = blockIdx.y;
  const int b = blockIdx.z;
  float A[D_STATE], h[D_STATE];
  const size_t sidx = (((size_t)b*NC + c)*D_INNER + d)*16;
  #pragma unroll
  for (int n = 0; n < D_STATE; ++n)
    A[n] = -__expf(alog[(size_t)d*D_STATE + n]);
  #pragma unroll
  for (int i = 0; i < 4; ++i) {
    float4 hq = *reinterpret_cast<const float4*>(hstate + sidx + 4*i);
    h[4*i+0]=hq.x; h[4*i+1]=hq.y; h[4*i+2]=hq.z; h[4*i+3]=hq.w;
  }
  const float dp = Dp[d];
  const size_t r0 = (size_t)b*LL + (size_t)c*CS;
  const size_t base = r0*D_INNER + d;
  const float* xrow = xdb + r0*64;
  for (int t = 0; t < CS; ++t) {
    float dlt = delta[base + (size_t)t*D_INNER];
    float xv  = xc[base + (size_t)t*D_INNER];
    float dx = dlt * xv;
    const float4* bc = reinterpret_cast<const float4*>(xrow + t*64 + 32);
    float Bv[D_STATE], Cv[D_STATE];
    #pragma unroll
    for (int i = 0; i < 4; ++i) {
      float4 bq = bc[i], cq = bc[4+i];
      Bv[4*i+0]=bq.x; Bv[4*i+1]=bq.y; Bv[4*i+2]=bq.z; Bv[4*i+3]=bq.w;
      Cv[4*i+0]=cq.x; Cv[4*i+1]=cq.y; Cv[4*i+2]=cq.z; Cv[4*i+3]=cq.w;
    }
    float acc = 0.f;
    #pragma unroll
    for (int n = 0; n < D_STATE; ++n) {
      float e = __expf(dlt*A[n]);
      h[n] = e*h[n] + dx*Bv[n];
      acc += h[n]*Cv[n];
    }
    const size_t rowoff = (r0 + t)*(2*D_INNER);
    float z = xz[rowoff + D_INNER + d];
    float sz = z / (1.f + __expf(-z));
    xz[rowoff + d] = (acc + xv*dp) * sz;
  }
}

// ---------------- K8: attn = y2 @ out_proj_w.T   [4096][512] fp32 -----------------------
// y2 lives in xz's xm half: row stride 2*D_INNER
__global__ void k_outproj(const float* __restrict__ y2,   // [4096][.] ld=2048
                          const float* __restrict__ w,    // [512][1024]
                          float* __restrict__ attn) {     // [4096][512]
  __shared__ float As[16][68];
  __shared__ float Bs[16][68];
  const int tx = threadIdx.x, ty = threadIdx.y;
  const int t = ty*16 + tx;
  const int row0 = blockIdx.y*64;
  const int col0 = blockIdx.x*64;
  float acc[4][4] = {};
  for (int k0 = 0; k0 < D_INNER; k0 += 16) {
    #pragma unroll
    for (int i = 0; i < 4; ++i) {
      int e = t + i*256;
      int kk = e & 15, rr = e >> 4;
      As[kk][rr] = y2[(size_t)(row0+rr)*(2*D_INNER) + k0+kk];
      Bs[kk][rr] = w[(size_t)(col0+rr)*D_INNER + k0+kk];
    }
    __syncthreads();
    #pragma unroll
    for (int kk = 0; kk < 16; ++kk) {
      float4 av = *reinterpret_cast<const float4*>(&As[kk][ty*4]);
      float4 bv = *reinterpret_cast<const float4*>(&Bs[kk][tx*4]);
      float a[4] = {av.x, av.y, av.z, av.w};
      float bq[4] = {bv.x, bv.y, bv.z, bv.w};
      #pragma unroll
      for (int i = 0; i < 4; ++i)
        #pragma unroll
        for (int j = 0; j < 4; ++j)
          acc[i][j] += a[i]*bq[j];
    }
    __syncthreads();
  }
  #pragma unroll
  for (int i = 0; i < 4; ++i) {
    float4 v = make_float4(acc[i][0], acc[i][1], acc[i][2], acc[i][3]);
    *reinterpret_cast<float4*>(&attn[(size_t)(row0+ty*4+i)*D_MODEL + col0 + tx*4]) = v;
  }
}

// ---------------- K9: out = LN(q + attn) * g + b  -> fp32 -------------------------------
__global__ void k_ln(const float* __restrict__ attn,
                     const float* __restrict__ q,
                     const float* __restrict__ g,
                     const float* __restrict__ bb,
                     float* __restrict__ out) {
  const int r = blockIdx.x;
  const int t = threadIdx.x;
  float v0 = attn[(size_t)r*D_MODEL + t]       + q[(size_t)r*D_MODEL + t];
  float v1 = attn[(size_t)r*D_MODEL + 256 + t] + q[(size_t)r*D_MODEL + 256 + t];
  float s = v0 + v1, sq = v0*v0 + v1*v1;
  #pragma unroll
  for (int off = 32; off; off >>= 1) {
    s  += __shfl_xor(s, off);
    sq += __shfl_xor(sq, off);
  }
  __shared__ float ss[4], qq[4], stats[2];
  const int wid = t >> 6, lane = t & 63;
  if (lane == 0) { ss[wid] = s; qq[wid] = sq; }
  __syncthreads();
  if (t == 0) {
    float S = ss[0]+ss[1]+ss[2]+ss[3];
    float Q = qq[0]+qq[1]+qq[2]+qq[3];
    float mu = S * (1.f/D_MODEL);
    float var = Q * (1.f/D_MODEL) - mu*mu;
    stats[0] = mu; stats[1] = rsqrtf(var + 1e-5f);
  }
  __syncthreads();
  float mu = stats[0], rs = stats[1];
  out[(size_t)r*D_MODEL + t]       = (v0-mu)*rs*g[t]     + bb[t];
  out[(size_t)r*D_MODEL + 256 + t] = (v1-mu)*rs*g[256+t] + bb[256+t];
}

extern "C" void kernel_launch(void* const* d_in, const int* in_sizes, int n_in,
                              void* d_out, int out_size, void* d_ws, size_t ws_size,
                              hipStream_t stream) {
  (void)in_sizes; (void)n_in; (void)out_size; (void)ws_size;
  const float* q    = (const float*)d_in[0];
  // d_in[1] (value) unused by reference
  const float* diff = (const float*)d_in[2];
  const float* aw   = (const float*)d_in[3];
  const float* ab   = (const float*)d_in[4];
  const float* inw  = (const float*)d_in[5];
  const float* cw   = (const float*)d_in[6];
  const float* cb   = (const float*)d_in[7];
  const float* xw   = (const float*)d_in[8];
  const float* dtw  = (const float*)d_in[9];
  const float* dtb  = (const float*)d_in[10];
  const float* alog = (const float*)d_in[11];
  const float* Dp   = (const float*)d_in[12];
  const float* outw = (const float*)d_in[13];
  const float* lng  = (const float*)d_in[14];
  const float* lnb  = (const float*)d_in[15];
  float* out = (float*)d_out;

  float* ws = (float*)d_ws;
  // workspace layout (floats) — total 21,235,712 floats (~85 MB), same as prev round
  float* m      = ws;                               // 2048
  float* xz     = ws + 2048;                        // 4096*2048
  float* xc     = xz + (size_t)RR*2*D_INNER;        // 4096*1024
  float* xdb    = xc + (size_t)RR*D_INNER;          // 4096*64
  float* delta  = xdb + (size_t)RR*64;              // 4096*1024
  float* aprod  = delta + (size_t)RR*D_INNER;       // 2*64*1024*16 = 2,097,152
  float* hstate = aprod + (size_t)BB*NC*D_INNER*16; // 2,097,152
  float* attn   = delta;                            // reuse (delta dead after k_scan3)

  k_ada<<<dim3(4,2), 256, 0, stream>>>(diff, aw, ab, m);
  k_inproj<<<dim3((2*D_INNER)/64, RR/64), dim3(16,16), 0, stream>>>(q, inw, m, xz);
  k_conv<<<(RR*D_INNER)/256, 256, 0, stream>>>(xz, cw, cb, xc);
  k_xproj<<<(RR*64)/256, 256, 0, stream>>>(xc, xw, xdb);
  k_delta<<<(RR*D_INNER)/256, 256, 0, stream>>>(xdb, dtw, dtb, delta);
  k_scan1<<<dim3(D_INNER/256, NC, BB), 256, 0, stream>>>(delta, xc, xdb, alog, aprod, hstate);
  k_scan2<<<(BB*D_INNER*16)/256, 256, 0, stream>>>(aprod, hstate);
  k_scan3<<<dim3(D_INNER/256, NC, BB), 256, 0, stream>>>(delta, xc, xdb, alog, hstate, Dp, xz);
  k_outproj<<<dim3(D_MODEL/64, RR/64), dim3(16,16), 0, stream>>>(xz, outw, attn);
  k_ln<<<RR, 256, 0, stream>>>(attn, q, lng, lnb, out);
}

// Round 4
// 404.567 us; speedup vs baseline: 3.7221x; 1.5183x over previous
//
#include <hip/hip_runtime.h>
#include <hip/hip_bf16.h>

#define D_MODEL 512
#define D_INNER 1024
#define D_STATE 16
#define DT_RANK 32
#define BB 2
#define LL 2048
#define RR (BB*LL)   // 4096
#define NC 64        // chunks per sequence
#define CS 32        // chunk size (NC*CS == LL)

typedef __attribute__((ext_vector_type(8))) short short8;
typedef __attribute__((ext_vector_type(4))) float f32x4;

static __device__ __forceinline__ short f2bf(float f) {
  union { __hip_bfloat16 h; short s; } u;
  u.h = __float2bfloat16(f);
  return u.s;
}

// ---------------- K1: m = silu(diff) @ ada_w.T + ada_b  (m: [2][1024] fp32) ------------
__global__ void k_ada(const float* __restrict__ diff,
                      const float* __restrict__ aw,
                      const float* __restrict__ ab,
                      float* __restrict__ m) {
  __shared__ float sd[D_MODEL];
  const int b = blockIdx.y;
  const int t = threadIdx.x;
  for (int k = t; k < D_MODEL; k += 256) {
    float v = diff[b*D_MODEL + k];
    sd[k] = v / (1.f + __expf(-v));
  }
  __syncthreads();
  const int j = blockIdx.x*256 + t;  // 0..1023
  const float4* wr = reinterpret_cast<const float4*>(aw + (size_t)j*D_MODEL);
  float acc = ab[j];
  #pragma unroll 4
  for (int k4 = 0; k4 < D_MODEL/4; ++k4) {
    float4 wv = wr[k4];
    acc += sd[4*k4]*wv.x + sd[4*k4+1]*wv.y + sd[4*k4+2]*wv.z + sd[4*k4+3]*wv.w;
  }
  m[b*(2*D_MODEL) + j] = acc;
}

// ---------------- K2: xz = (q*(1+scale)+shift) @ in_proj_w.T  via bf16 MFMA -------------
// C[4096][2048] = Amod[4096][512] x W[2048][512]^T   (both K-contiguous)
__global__ void __launch_bounds__(256) k_inproj_mfma(
    const float* __restrict__ q,     // [4096][512]
    const float* __restrict__ w,     // [2048][512]
    const float* __restrict__ m,     // [2][1024] (scale | shift per 512)
    float* __restrict__ xz) {        // [4096][2048]
  __shared__ short As[64][48];   // 64 rows x 32 k, pad to 48 (96B stride, 16B aligned)
  __shared__ short Bs[64][48];
  const int t = threadIdx.x;
  const int wave = t >> 6, lane = t & 63;
  const int quad = lane >> 4, l16 = lane & 15;
  const int row0 = blockIdx.y*64;
  const int col0 = blockIdx.x*64;
  const float* mrow = m + (row0 >> 11)*(2*D_MODEL);
  const int tr = t >> 2;          // 0..63
  const int tk = (t & 3)*8;       // 0,8,16,24
  f32x4 acc[4] = {};
  for (int k0 = 0; k0 < D_MODEL; k0 += 32) {
    // stage A (modulated) and B, fp32 -> bf16
    {
      const float* ap = q + (size_t)(row0+tr)*D_MODEL + k0 + tk;
      float4 a0 = *reinterpret_cast<const float4*>(ap);
      float4 a1 = *reinterpret_cast<const float4*>(ap+4);
      float4 s0 = *reinterpret_cast<const float4*>(mrow + k0 + tk);
      float4 s1 = *reinterpret_cast<const float4*>(mrow + k0 + tk + 4);
      float4 h0 = *reinterpret_cast<const float4*>(mrow + D_MODEL + k0 + tk);
      float4 h1 = *reinterpret_cast<const float4*>(mrow + D_MODEL + k0 + tk + 4);
      short8 av;
      av[0]=f2bf(a0.x*(1.f+s0.x)+h0.x); av[1]=f2bf(a0.y*(1.f+s0.y)+h0.y);
      av[2]=f2bf(a0.z*(1.f+s0.z)+h0.z); av[3]=f2bf(a0.w*(1.f+s0.w)+h0.w);
      av[4]=f2bf(a1.x*(1.f+s1.x)+h1.x); av[5]=f2bf(a1.y*(1.f+s1.y)+h1.y);
      av[6]=f2bf(a1.z*(1.f+s1.z)+h1.z); av[7]=f2bf(a1.w*(1.f+s1.w)+h1.w);
      *reinterpret_cast<short8*>(&As[tr][tk]) = av;
      const float* bp = w + (size_t)(col0+tr)*D_MODEL + k0 + tk;
      float4 b0 = *reinterpret_cast<const float4*>(bp);
      float4 b1 = *reinterpret_cast<const float4*>(bp+4);
      short8 bv;
      bv[0]=f2bf(b0.x); bv[1]=f2bf(b0.y); bv[2]=f2bf(b0.z); bv[3]=f2bf(b0.w);
      bv[4]=f2bf(b1.x); bv[5]=f2bf(b1.y); bv[6]=f2bf(b1.z); bv[7]=f2bf(b1.w);
      *reinterpret_cast<short8*>(&Bs[tr][tk]) = bv;
    }
    __syncthreads();
    short8 af = *reinterpret_cast<const short8*>(&As[wave*16 + l16][quad*8]);
    #pragma unroll
    for (int nt = 0; nt < 4; ++nt) {
      short8 bf = *reinterpret_cast<const short8*>(&Bs[nt*16 + l16][quad*8]);
      acc[nt] = __builtin_amdgcn_mfma_f32_16x16x32_bf16(af, bf, acc[nt], 0, 0, 0);
    }
    __syncthreads();
  }
  #pragma unroll
  for (int nt = 0; nt < 4; ++nt)
    #pragma unroll
    for (int r = 0; r < 4; ++r)
      xz[(size_t)(row0 + wave*16 + quad*4 + r)*(2*D_INNER) + col0 + nt*16 + l16] = acc[nt][r];
}

// ---------------- K8: attn = y2 @ out_proj_w.T  via bf16 MFMA ---------------------------
// A = y2 in xz's xm half (lda = 2048), B = outw [512][1024]
__global__ void __launch_bounds__(256) k_outproj_mfma(
    const float* __restrict__ y2,    // ld 2048
    const float* __restrict__ w,     // [512][1024]
    float* __restrict__ attn) {      // [4096][512]
  __shared__ short As[64][48];
  __shared__ short Bs[64][48];
  const int t = threadIdx.x;
  const int wave = t >> 6, lane = t & 63;
  const int quad = lane >> 4, l16 = lane & 15;
  const int row0 = blockIdx.y*64;
  const int col0 = blockIdx.x*64;
  const int tr = t >> 2;
  const int tk = (t & 3)*8;
  f32x4 acc[4] = {};
  for (int k0 = 0; k0 < D_INNER; k0 += 32) {
    {
      const float* ap = y2 + (size_t)(row0+tr)*(2*D_INNER) + k0 + tk;
      float4 a0 = *reinterpret_cast<const float4*>(ap);
      float4 a1 = *reinterpret_cast<const float4*>(ap+4);
      short8 av;
      av[0]=f2bf(a0.x); av[1]=f2bf(a0.y); av[2]=f2bf(a0.z); av[3]=f2bf(a0.w);
      av[4]=f2bf(a1.x); av[5]=f2bf(a1.y); av[6]=f2bf(a1.z); av[7]=f2bf(a1.w);
      *reinterpret_cast<short8*>(&As[tr][tk]) = av;
      const float* bp = w + (size_t)(col0+tr)*D_INNER + k0 + tk;
      float4 b0 = *reinterpret_cast<const float4*>(bp);
      float4 b1 = *reinterpret_cast<const float4*>(bp+4);
      short8 bv;
      bv[0]=f2bf(b0.x); bv[1]=f2bf(b0.y); bv[2]=f2bf(b0.z); bv[3]=f2bf(b0.w);
      bv[4]=f2bf(b1.x); bv[5]=f2bf(b1.y); bv[6]=f2bf(b1.z); bv[7]=f2bf(b1.w);
      *reinterpret_cast<short8*>(&Bs[tr][tk]) = bv;
    }
    __syncthreads();
    short8 af = *reinterpret_cast<const short8*>(&As[wave*16 + l16][quad*8]);
    #pragma unroll
    for (int nt = 0; nt < 4; ++nt) {
      short8 bf = *reinterpret_cast<const short8*>(&Bs[nt*16 + l16][quad*8]);
      acc[nt] = __builtin_amdgcn_mfma_f32_16x16x32_bf16(af, bf, acc[nt], 0, 0, 0);
    }
    __syncthreads();
  }
  #pragma unroll
  for (int nt = 0; nt < 4; ++nt)
    #pragma unroll
    for (int r = 0; r < 4; ++r)
      attn[(size_t)(row0 + wave*16 + quad*4 + r)*D_MODEL + col0 + nt*16 + l16] = acc[nt][r];
}

// ---------------- K3: xc = silu(causal_conv4(xm) + conv_b)   [4096][1024] fp32 ----------
__global__ void k_conv(const float* __restrict__ xz,
                       const float* __restrict__ cw,  // [1024][4]
                       const float* __restrict__ cb,
                       float* __restrict__ xc) {
  const int gid = blockIdx.x*256 + threadIdx.x;   // over 4096*1024
  const int d = gid & (D_INNER-1);
  const int r = gid >> 10;
  const int l = r & (LL-1);
  float4 cv = *reinterpret_cast<const float4*>(cw + (size_t)d*4);
  float wv[4] = {cv.x, cv.y, cv.z, cv.w};
  float acc = cb[d];
  #pragma unroll
  for (int k = 0; k < 4; ++k) {
    int ls = l + k - 3;
    if (ls >= 0) acc += xz[(size_t)(r + k - 3)*(2*D_INNER) + d] * wv[k];
  }
  xc[gid] = acc / (1.f + __expf(-acc));
}

// ---------------- K4: xdb = xc @ x_proj_w.T  (fp32 LDS-tiled, M=4096 N=64 K=1024) -------
__global__ void k_xproj_t(const float* __restrict__ xc,   // [4096][1024]
                          const float* __restrict__ xw,   // [64][1024]
                          float* __restrict__ xdb) {      // [4096][64]
  __shared__ float As[16][68];
  __shared__ float Bs[16][68];
  const int tx = threadIdx.x, ty = threadIdx.y;
  const int t = ty*16 + tx;
  const int row0 = blockIdx.y*64;
  float acc[4][4] = {};
  for (int k0 = 0; k0 < D_INNER; k0 += 16) {
    #pragma unroll
    for (int i = 0; i < 4; ++i) {
      int e = t + i*256;
      int kk = e & 15, rr = e >> 4;
      As[kk][rr] = xc[(size_t)(row0+rr)*D_INNER + k0+kk];
      Bs[kk][rr] = xw[(size_t)rr*D_INNER + k0+kk];
    }
    __syncthreads();
    #pragma unroll
    for (int kk = 0; kk < 16; ++kk) {
      float4 av = *reinterpret_cast<const float4*>(&As[kk][ty*4]);
      float4 bv = *reinterpret_cast<const float4*>(&Bs[kk][tx*4]);
      float a[4] = {av.x, av.y, av.z, av.w};
      float bq[4] = {bv.x, bv.y, bv.z, bv.w};
      #pragma unroll
      for (int i = 0; i < 4; ++i)
        #pragma unroll
        for (int j = 0; j < 4; ++j)
          acc[i][j] += a[i]*bq[j];
    }
    __syncthreads();
  }
  #pragma unroll
  for (int i = 0; i < 4; ++i) {
    float4 v = make_float4(acc[i][0], acc[i][1], acc[i][2], acc[i][3]);
    *reinterpret_cast<float4*>(&xdb[(size_t)(row0+ty*4+i)*64 + tx*4]) = v;
  }
}

// ---------------- K5: delta = softplus(dt @ dt_proj_w.T + dt_proj_b)  [4096][1024] ------
__global__ void k_delta(const float* __restrict__ xdb,
                        const float* __restrict__ dw,  // [1024][32]
                        const float* __restrict__ db,
                        float* __restrict__ delta) {
  const int gid = blockIdx.x*256 + threadIdx.x;   // 4096*1024
  const int d = gid & (D_INNER-1), r = gid >> 10;
  const float4* xr = reinterpret_cast<const float4*>(xdb + (size_t)r*64);
  const float4* wr = reinterpret_cast<const float4*>(dw + (size_t)d*DT_RANK);
  float acc = db[d];
  #pragma unroll
  for (int i = 0; i < DT_RANK/4; ++i) {
    float4 xv = xr[i];
    float4 wv = wr[i];
    acc += xv.x*wv.x + xv.y*wv.y + xv.z*wv.z + xv.w*wv.w;
  }
  delta[gid] = (acc > 20.f) ? acc : __logf(1.f + __expf(acc));
}

// ---------------- K6a: chunk-local scan (h from 0) + decay product ----------------------
__global__ void __launch_bounds__(256) k_scan1(
    const float* __restrict__ delta,
    const float* __restrict__ xc,
    const float* __restrict__ xdb,
    const float* __restrict__ alog,
    float* __restrict__ aprod,
    float* __restrict__ hstate) {
  const int d = blockIdx.x*256 + threadIdx.x;
  const int c = blockIdx.y;
  const int b = blockIdx.z;
  float A[D_STATE], ap[D_STATE], h[D_STATE];
  #pragma unroll
  for (int n = 0; n < D_STATE; ++n) {
    A[n] = -__expf(alog[(size_t)d*D_STATE + n]);
    ap[n] = 1.f; h[n] = 0.f;
  }
  const size_t base = ((size_t)b*LL + (size_t)c*CS)*D_INNER + d;
  const float* xrow = xdb + ((size_t)b*LL + (size_t)c*CS)*64;
  for (int t = 0; t < CS; ++t) {
    float dlt = delta[base + (size_t)t*D_INNER];
    float xv  = xc[base + (size_t)t*D_INNER];
    float dx = dlt * xv;
    const float4* bptr = reinterpret_cast<const float4*>(xrow + t*64 + 32);
    float Bv[D_STATE];
    #pragma unroll
    for (int i = 0; i < 4; ++i) {
      float4 bq = bptr[i];
      Bv[4*i+0]=bq.x; Bv[4*i+1]=bq.y; Bv[4*i+2]=bq.z; Bv[4*i+3]=bq.w;
    }
    #pragma unroll
    for (int n = 0; n < D_STATE; ++n) {
      float e = __expf(dlt*A[n]);
      ap[n] *= e;
      h[n] = e*h[n] + dx*Bv[n];
    }
  }
  const size_t sidx = (((size_t)b*NC + c)*D_INNER + d)*16;
  #pragma unroll
  for (int i = 0; i < 4; ++i) {
    *reinterpret_cast<float4*>(aprod + sidx + 4*i) =
        make_float4(ap[4*i], ap[4*i+1], ap[4*i+2], ap[4*i+3]);
    *reinterpret_cast<float4*>(hstate + sidx + 4*i) =
        make_float4(h[4*i], h[4*i+1], h[4*i+2], h[4*i+3]);
  }
}

// ---------------- K6b: combine chunk states; hstate[c] becomes INCOMING state -----------
__global__ void k_scan2(const float* __restrict__ aprod,
                        float* __restrict__ hstate) {
  const int gid = blockIdx.x*256 + threadIdx.x;   // over BB*D_INNER*16 = 32768
  const int b = gid >> 14;
  const int dn = gid & 16383;
  float h = 0.f;
  for (int c = 0; c < NC; ++c) {
    const size_t idx = ((size_t)(b*NC + c))*D_INNER*16 + dn;
    float a  = aprod[idx];
    float hl = hstate[idx];
    hstate[idx] = h;
    h = a*h + hl;
  }
}

// ---------------- K6c: re-scan seeded + fused gate; writes y2 into xz xm-half -----------
__global__ void __launch_bounds__(256) k_scan3(
    const float* __restrict__ delta,
    const float* __restrict__ xc,
    const float* __restrict__ xdb,
    const float* __restrict__ alog,
    const float* __restrict__ hstate,
    const float* __restrict__ Dp,
    float* xz) {
  const int d = blockIdx.x*256 + threadIdx.x;
  const int c = blockIdx.y;
  const int b = blockIdx.z;
  float A[D_STATE], h[D_STATE];
  const size_t sidx = (((size_t)b*NC + c)*D_INNER + d)*16;
  #pragma unroll
  for (int n = 0; n < D_STATE; ++n)
    A[n] = -__expf(alog[(size_t)d*D_STATE + n]);
  #pragma unroll
  for (int i = 0; i < 4; ++i) {
    float4 hq = *reinterpret_cast<const float4*>(hstate + sidx + 4*i);
    h[4*i+0]=hq.x; h[4*i+1]=hq.y; h[4*i+2]=hq.z; h[4*i+3]=hq.w;
  }
  const float dp = Dp[d];
  const size_t r0 = (size_t)b*LL + (size_t)c*CS;
  const size_t base = r0*D_INNER + d;
  const float* xrow = xdb + r0*64;
  for (int t = 0; t < CS; ++t) {
    float dlt = delta[base + (size_t)t*D_INNER];
    float xv  = xc[base + (size_t)t*D_INNER];
    float dx = dlt * xv;
    const float4* bc = reinterpret_cast<const float4*>(xrow + t*64 + 32);
    float Bv[D_STATE], Cv[D_STATE];
    #pragma unroll
    for (int i = 0; i < 4; ++i) {
      float4 bq = bc[i], cq = bc[4+i];
      Bv[4*i+0]=bq.x; Bv[4*i+1]=bq.y; Bv[4*i+2]=bq.z; Bv[4*i+3]=bq.w;
      Cv[4*i+0]=cq.x; Cv[4*i+1]=cq.y; Cv[4*i+2]=cq.z; Cv[4*i+3]=cq.w;
    }
    float acc = 0.f;
    #pragma unroll
    for (int n = 0; n < D_STATE; ++n) {
      float e = __expf(dlt*A[n]);
      h[n] = e*h[n] + dx*Bv[n];
      acc += h[n]*Cv[n];
    }
    const size_t rowoff = (r0 + t)*(2*D_INNER);
    float z = xz[rowoff + D_INNER + d];
    float sz = z / (1.f + __expf(-z));
    xz[rowoff + d] = (acc + xv*dp) * sz;
  }
}

// ---------------- K9: out = LN(q + attn) * g + b  -> fp32 -------------------------------
__global__ void k_ln(const float* __restrict__ attn,
                     const float* __restrict__ q,
                     const float* __restrict__ g,
                     const float* __restrict__ bb,
                     float* __restrict__ out) {
  const int r = blockIdx.x;
  const int t = threadIdx.x;
  float v0 = attn[(size_t)r*D_MODEL + t]       + q[(size_t)r*D_MODEL + t];
  float v1 = attn[(size_t)r*D_MODEL + 256 + t] + q[(size_t)r*D_MODEL + 256 + t];
  float s = v0 + v1, sq = v0*v0 + v1*v1;
  #pragma unroll
  for (int off = 32; off; off >>= 1) {
    s  += __shfl_xor(s, off);
    sq += __shfl_xor(sq, off);
  }
  __shared__ float ss[4], qq[4], stats[2];
  const int wid = t >> 6, lane = t & 63;
  if (lane == 0) { ss[wid] = s; qq[wid] = sq; }
  __syncthreads();
  if (t == 0) {
    float S = ss[0]+ss[1]+ss[2]+ss[3];
    float Q = qq[0]+qq[1]+qq[2]+qq[3];
    float mu = S * (1.f/D_MODEL);
    float var = Q * (1.f/D_MODEL) - mu*mu;
    stats[0] = mu; stats[1] = rsqrtf(var + 1e-5f);
  }
  __syncthreads();
  float mu = stats[0], rs = stats[1];
  out[(size_t)r*D_MODEL + t]       = (v0-mu)*rs*g[t]     + bb[t];
  out[(size_t)r*D_MODEL + 256 + t] = (v1-mu)*rs*g[256+t] + bb[256+t];
}

extern "C" void kernel_launch(void* const* d_in, const int* in_sizes, int n_in,
                              void* d_out, int out_size, void* d_ws, size_t ws_size,
                              hipStream_t stream) {
  (void)in_sizes; (void)n_in; (void)out_size; (void)ws_size;
  const float* q    = (const float*)d_in[0];
  const float* diff = (const float*)d_in[2];
  const float* aw   = (const float*)d_in[3];
  const float* ab   = (const float*)d_in[4];
  const float* inw  = (const float*)d_in[5];
  const float* cw   = (const float*)d_in[6];
  const float* cb   = (const float*)d_in[7];
  const float* xw   = (const float*)d_in[8];
  const float* dtw  = (const float*)d_in[9];
  const float* dtb  = (const float*)d_in[10];
  const float* alog = (const float*)d_in[11];
  const float* Dp   = (const float*)d_in[12];
  const float* outw = (const float*)d_in[13];
  const float* lng  = (const float*)d_in[14];
  const float* lnb  = (const float*)d_in[15];
  float* out = (float*)d_out;

  float* ws = (float*)d_ws;
  float* m      = ws;                               // 2048
  float* xz     = ws + 2048;                        // 4096*2048
  float* xc     = xz + (size_t)RR*2*D_INNER;        // 4096*1024
  float* xdb    = xc + (size_t)RR*D_INNER;          // 4096*64
  float* delta  = xdb + (size_t)RR*64;              // 4096*1024
  float* aprod  = delta + (size_t)RR*D_INNER;       // 2*64*1024*16
  float* hstate = aprod + (size_t)BB*NC*D_INNER*16; // 2*64*1024*16
  float* attn   = delta;                            // reuse (delta dead after k_scan3)

  k_ada<<<dim3(4,2), 256, 0, stream>>>(diff, aw, ab, m);
  k_inproj_mfma<<<dim3((2*D_INNER)/64, RR/64), 256, 0, stream>>>(q, inw, m, xz);
  k_conv<<<(RR*D_INNER)/256, 256, 0, stream>>>(xz, cw, cb, xc);
  k_xproj_t<<<dim3(1, RR/64), dim3(16,16), 0, stream>>>(xc, xw, xdb);
  k_delta<<<(RR*D_INNER)/256, 256, 0, stream>>>(xdb, dtw, dtb, delta);
  k_scan1<<<dim3(D_INNER/256, NC, BB), 256, 0, stream>>>(delta, xc, xdb, alog, aprod, hstate);
  k_scan2<<<(BB*D_INNER*16)/256, 256, 0, stream>>>(aprod, hstate);
  k_scan3<<<dim3(D_INNER/256, NC, BB), 256, 0, stream>>>(delta, xc, xdb, alog, hstate, Dp, xz);
  k_outproj_mfma<<<dim3(D_MODEL/64, RR/64), 256, 0, stream>>>(xz, outw, attn);
  k_ln<<<RR, 256, 0, stream>>>(attn, q, lng, lnb, out);
}

// Round 5
// 309.115 us; speedup vs baseline: 4.8714x; 1.3088x over previous
//
#include <hip/hip_runtime.h>
#include <hip/hip_bf16.h>

#define D_MODEL 512
#define D_INNER 1024
#define D_STATE 16
#define DT_RANK 32
#define BB 2
#define LL 2048
#define RR (BB*LL)   // 4096
#define NC 64        // chunks per sequence
#define CS 32        // chunk size (NC*CS == LL)

typedef __attribute__((ext_vector_type(8))) short short8;
typedef __attribute__((ext_vector_type(4))) short short4v;
typedef __attribute__((ext_vector_type(4))) float f32x4;

static __device__ __forceinline__ short f2bf(float f) {
  union { __hip_bfloat16 h; short s; } u;
  u.h = __float2bfloat16(f);
  return u.s;
}

// ---------------- K1: m = silu(diff) @ ada_w.T + ada_b  (m: [2][1024] fp32) ------------
__global__ void k_ada(const float* __restrict__ diff,
                      const float* __restrict__ aw,
                      const float* __restrict__ ab,
                      float* __restrict__ m) {
  __shared__ float sd[D_MODEL];
  const int b = blockIdx.y;
  const int t = threadIdx.x;
  for (int k = t; k < D_MODEL; k += 256) {
    float v = diff[b*D_MODEL + k];
    sd[k] = v / (1.f + __expf(-v));
  }
  __syncthreads();
  const int j = blockIdx.x*256 + t;  // 0..1023
  const float4* wr = reinterpret_cast<const float4*>(aw + (size_t)j*D_MODEL);
  float acc = ab[j];
  #pragma unroll 4
  for (int k4 = 0; k4 < D_MODEL/4; ++k4) {
    float4 wv = wr[k4];
    acc += sd[4*k4]*wv.x + sd[4*k4+1]*wv.y + sd[4*k4+2]*wv.z + sd[4*k4+3]*wv.w;
  }
  m[b*(2*D_MODEL) + j] = acc;
}

// ---------------- K1b: convert in_proj_w and out_proj_w to bf16 (once) ------------------
__global__ void k_cvtw(const float* __restrict__ inw,   // 2048*512
                       const float* __restrict__ outw,  // 512*1024
                       short* __restrict__ inwb,
                       short* __restrict__ outwb) {
  const int N1 = 2048*512, N2 = 512*1024;
  int gid = blockIdx.x*256 + threadIdx.x;
  const int idx = gid*4;
  if (idx < N1) {
    float4 v = *reinterpret_cast<const float4*>(inw + idx);
    short4v s = {f2bf(v.x), f2bf(v.y), f2bf(v.z), f2bf(v.w)};
    *reinterpret_cast<short4v*>(inwb + idx) = s;
  } else if (idx < N1 + N2) {
    float4 v = *reinterpret_cast<const float4*>(outw + (idx - N1));
    short4v s = {f2bf(v.x), f2bf(v.y), f2bf(v.z), f2bf(v.w)};
    *reinterpret_cast<short4v*>(outwb + (idx - N1)) = s;
  }
}

// ---------------- K1c: amod = bf16(q*(1+scale)+shift)   [4096][512] bf16 ----------------
__global__ void k_amod(const float* __restrict__ q,
                       const float* __restrict__ m,
                       short* __restrict__ amod) {
  const int gid = blockIdx.x*256 + threadIdx.x;   // over 4096*512/4
  const int idx = gid*4;
  const int r = idx >> 9, k = idx & 511;
  const float* mrow = m + (r >> 11)*(2*D_MODEL);
  float4 a = *reinterpret_cast<const float4*>(q + idx);
  float4 s = *reinterpret_cast<const float4*>(mrow + k);
  float4 h = *reinterpret_cast<const float4*>(mrow + D_MODEL + k);
  short4v o = {f2bf(a.x*(1.f+s.x)+h.x), f2bf(a.y*(1.f+s.y)+h.y),
               f2bf(a.z*(1.f+s.z)+h.z), f2bf(a.w*(1.f+s.w)+h.w)};
  *reinterpret_cast<short4v*>(amod + idx) = o;
}

// ---------------- unified bf16 MFMA GEMM: C[M][N] = A[M][K] x B[N][K]^T -----------------
// grid (N/64, M/64), 256 threads (4 waves). C fp32 with leading dim ldc.
__global__ void __launch_bounds__(256) k_gemm_bf16(
    const short* __restrict__ A,
    const short* __restrict__ B,
    float* __restrict__ C,
    int K, int ldc) {
  __shared__ short As[64][48];
  __shared__ short Bs[64][48];
  const int t = threadIdx.x;
  const int wave = t >> 6, lane = t & 63;
  const int quad = lane >> 4, l16 = lane & 15;
  const int row0 = blockIdx.y*64;
  const int col0 = blockIdx.x*64;
  const int tr = t >> 2;          // 0..63
  const int tk = (t & 3)*8;       // 0,8,16,24
  f32x4 acc[4] = {};
  for (int k0 = 0; k0 < K; k0 += 32) {
    *reinterpret_cast<short8*>(&As[tr][tk]) =
        *reinterpret_cast<const short8*>(A + (size_t)(row0+tr)*K + k0 + tk);
    *reinterpret_cast<short8*>(&Bs[tr][tk]) =
        *reinterpret_cast<const short8*>(B + (size_t)(col0+tr)*K + k0 + tk);
    __syncthreads();
    short8 af = *reinterpret_cast<const short8*>(&As[wave*16 + l16][quad*8]);
    #pragma unroll
    for (int nt = 0; nt < 4; ++nt) {
      short8 bf = *reinterpret_cast<const short8*>(&Bs[nt*16 + l16][quad*8]);
      acc[nt] = __builtin_amdgcn_mfma_f32_16x16x32_bf16(af, bf, acc[nt], 0, 0, 0);
    }
    __syncthreads();
  }
  #pragma unroll
  for (int nt = 0; nt < 4; ++nt)
    #pragma unroll
    for (int r = 0; r < 4; ++r)
      C[(size_t)(row0 + wave*16 + quad*4 + r)*ldc + col0 + nt*16 + l16] = acc[nt][r];
}

// ---------------- K3: xc = silu(causal_conv4(xm) + conv_b)   [4096][1024] fp32 ----------
__global__ void k_conv(const float* __restrict__ xz,
                       const float* __restrict__ cw,  // [1024][4]
                       const float* __restrict__ cb,
                       float* __restrict__ xc) {
  const int gid = blockIdx.x*256 + threadIdx.x;   // over 4096*1024
  const int d = gid & (D_INNER-1);
  const int r = gid >> 10;
  const int l = r & (LL-1);
  float4 cv = *reinterpret_cast<const float4*>(cw + (size_t)d*4);
  float wv[4] = {cv.x, cv.y, cv.z, cv.w};
  float acc = cb[d];
  #pragma unroll
  for (int k = 0; k < 4; ++k) {
    int ls = l + k - 3;
    if (ls >= 0) acc += xz[(size_t)(r + k - 3)*(2*D_INNER) + d] * wv[k];
  }
  xc[gid] = acc / (1.f + __expf(-acc));
}

// ---------------- K4: xdb += xc @ x_proj_w.T  (fp32, K-split x8, atomic accumulate) -----
__global__ void k_xproj_t(const float* __restrict__ xc,   // [4096][1024]
                          const float* __restrict__ xw,   // [64][1024]
                          float* __restrict__ xdb) {      // [4096][64] (pre-zeroed)
  __shared__ float As[16][68];
  __shared__ float Bs[16][68];
  const int tx = threadIdx.x, ty = threadIdx.y;
  const int t = ty*16 + tx;
  const int row0 = blockIdx.y*64;
  const int kbase = blockIdx.x*128;   // 8 chunks of 128
  float acc[4][4] = {};
  for (int k0 = kbase; k0 < kbase + 128; k0 += 16) {
    #pragma unroll
    for (int i = 0; i < 4; ++i) {
      int e = t + i*256;
      int kk = e & 15, rr = e >> 4;
      As[kk][rr] = xc[(size_t)(row0+rr)*D_INNER + k0+kk];
      Bs[kk][rr] = xw[(size_t)rr*D_INNER + k0+kk];
    }
    __syncthreads();
    #pragma unroll
    for (int kk = 0; kk < 16; ++kk) {
      float4 av = *reinterpret_cast<const float4*>(&As[kk][ty*4]);
      float4 bv = *reinterpret_cast<const float4*>(&Bs[kk][tx*4]);
      float a[4] = {av.x, av.y, av.z, av.w};
      float bq[4] = {bv.x, bv.y, bv.z, bv.w};
      #pragma unroll
      for (int i = 0; i < 4; ++i)
        #pragma unroll
        for (int j = 0; j < 4; ++j)
          acc[i][j] += a[i]*bq[j];
    }
    __syncthreads();
  }
  #pragma unroll
  for (int i = 0; i < 4; ++i)
    #pragma unroll
    for (int j = 0; j < 4; ++j)
      unsafeAtomicAdd(&xdb[(size_t)(row0+ty*4+i)*64 + tx*4 + j], acc[i][j]);
}

// ---------------- K6a: chunk-local scan + fused delta; outputs aprod/hstate -------------
__global__ void __launch_bounds__(256) k_scan1(
    const float* __restrict__ xc,
    const float* __restrict__ xdb,
    const float* __restrict__ alog,
    const float* __restrict__ dtw,   // [1024][32]
    const float* __restrict__ dtb,
    float* __restrict__ aprod,
    float* __restrict__ hstate) {
  const int d = blockIdx.x*256 + threadIdx.x;
  const int c = blockIdx.y;
  const int b = blockIdx.z;
  float A[D_STATE], ap[D_STATE], h[D_STATE], dwr[DT_RANK];
  const float4* dwp = reinterpret_cast<const float4*>(dtw + (size_t)d*DT_RANK);
  #pragma unroll
  for (int i = 0; i < 8; ++i) {
    float4 v = dwp[i];
    dwr[4*i]=v.x; dwr[4*i+1]=v.y; dwr[4*i+2]=v.z; dwr[4*i+3]=v.w;
  }
  const float dbv = dtb[d];
  #pragma unroll
  for (int n = 0; n < D_STATE; ++n) {
    A[n] = -__expf(alog[(size_t)d*D_STATE + n]);
    ap[n] = 1.f; h[n] = 0.f;
  }
  const size_t base = ((size_t)b*LL + (size_t)c*CS)*D_INNER + d;
  const float* xrow = xdb + ((size_t)b*LL + (size_t)c*CS)*64;
  for (int t = 0; t < CS; ++t) {
    const float4* dtp = reinterpret_cast<const float4*>(xrow + t*64);
    float dacc = dbv;
    #pragma unroll
    for (int i = 0; i < 8; ++i) {
      float4 v = dtp[i];
      dacc += v.x*dwr[4*i] + v.y*dwr[4*i+1] + v.z*dwr[4*i+2] + v.w*dwr[4*i+3];
    }
    float dlt = (dacc > 20.f) ? dacc : __logf(1.f + __expf(dacc));
    float xv  = xc[base + (size_t)t*D_INNER];
    float dx = dlt * xv;
    const float4* bptr = reinterpret_cast<const float4*>(xrow + t*64 + 32);
    float Bv[D_STATE];
    #pragma unroll
    for (int i = 0; i < 4; ++i) {
      float4 bq = bptr[i];
      Bv[4*i+0]=bq.x; Bv[4*i+1]=bq.y; Bv[4*i+2]=bq.z; Bv[4*i+3]=bq.w;
    }
    #pragma unroll
    for (int n = 0; n < D_STATE; ++n) {
      float e = __expf(dlt*A[n]);
      ap[n] *= e;
      h[n] = e*h[n] + dx*Bv[n];
    }
  }
  const size_t sidx = (((size_t)b*NC + c)*D_INNER + d)*16;
  #pragma unroll
  for (int i = 0; i < 4; ++i) {
    *reinterpret_cast<float4*>(aprod + sidx + 4*i) =
        make_float4(ap[4*i], ap[4*i+1], ap[4*i+2], ap[4*i+3]);
    *reinterpret_cast<float4*>(hstate + sidx + 4*i) =
        make_float4(h[4*i], h[4*i+1], h[4*i+2], h[4*i+3]);
  }
}

// ---------------- K6b: combine chunk states; hstate[c] becomes INCOMING state -----------
__global__ void k_scan2(const float* __restrict__ aprod,
                        float* __restrict__ hstate) {
  const int gid = blockIdx.x*256 + threadIdx.x;   // over BB*D_INNER*16 = 32768
  const int b = gid >> 14;
  const int dn = gid & 16383;
  float h = 0.f;
  for (int c = 0; c < NC; ++c) {
    const size_t idx = ((size_t)(b*NC + c))*D_INNER*16 + dn;
    float a  = aprod[idx];
    float hl = hstate[idx];
    hstate[idx] = h;
    h = a*h + hl;
  }
}

// ---------------- K6c: seeded re-scan + fused delta + fused gate -> y2b (bf16) ----------
__global__ void __launch_bounds__(256) k_scan3(
    const float* __restrict__ xc,
    const float* __restrict__ xdb,
    const float* __restrict__ alog,
    const float* __restrict__ dtw,
    const float* __restrict__ dtb,
    const float* __restrict__ hstate,
    const float* __restrict__ Dp,
    const float* __restrict__ xz,    // read z at +D_INNER
    short* __restrict__ y2b) {       // [4096][1024] bf16
  const int d = blockIdx.x*256 + threadIdx.x;
  const int c = blockIdx.y;
  const int b = blockIdx.z;
  float A[D_STATE], h[D_STATE], dwr[DT_RANK];
  const float4* dwp = reinterpret_cast<const float4*>(dtw + (size_t)d*DT_RANK);
  #pragma unroll
  for (int i = 0; i < 8; ++i) {
    float4 v = dwp[i];
    dwr[4*i]=v.x; dwr[4*i+1]=v.y; dwr[4*i+2]=v.z; dwr[4*i+3]=v.w;
  }
  const float dbv = dtb[d];
  const size_t sidx = (((size_t)b*NC + c)*D_INNER + d)*16;
  #pragma unroll
  for (int n = 0; n < D_STATE; ++n)
    A[n] = -__expf(alog[(size_t)d*D_STATE + n]);
  #pragma unroll
  for (int i = 0; i < 4; ++i) {
    float4 hq = *reinterpret_cast<const float4*>(hstate + sidx + 4*i);
    h[4*i+0]=hq.x; h[4*i+1]=hq.y; h[4*i+2]=hq.z; h[4*i+3]=hq.w;
  }
  const float dp = Dp[d];
  const size_t r0 = (size_t)b*LL + (size_t)c*CS;
  const size_t base = r0*D_INNER + d;
  const float* xrow = xdb + r0*64;
  for (int t = 0; t < CS; ++t) {
    const float4* dtp = reinterpret_cast<const float4*>(xrow + t*64);
    float dacc = dbv;
    #pragma unroll
    for (int i = 0; i < 8; ++i) {
      float4 v = dtp[i];
      dacc += v.x*dwr[4*i] + v.y*dwr[4*i+1] + v.z*dwr[4*i+2] + v.w*dwr[4*i+3];
    }
    float dlt = (dacc > 20.f) ? dacc : __logf(1.f + __expf(dacc));
    float xv  = xc[base + (size_t)t*D_INNER];
    float dx = dlt * xv;
    const float4* bc = reinterpret_cast<const float4*>(xrow + t*64 + 32);
    float Bv[D_STATE], Cv[D_STATE];
    #pragma unroll
    for (int i = 0; i < 4; ++i) {
      float4 bq = bc[i], cq = bc[4+i];
      Bv[4*i+0]=bq.x; Bv[4*i+1]=bq.y; Bv[4*i+2]=bq.z; Bv[4*i+3]=bq.w;
      Cv[4*i+0]=cq.x; Cv[4*i+1]=cq.y; Cv[4*i+2]=cq.z; Cv[4*i+3]=cq.w;
    }
    float acc = 0.f;
    #pragma unroll
    for (int n = 0; n < D_STATE; ++n) {
      float e = __expf(dlt*A[n]);
      h[n] = e*h[n] + dx*Bv[n];
      acc += h[n]*Cv[n];
    }
    float z = xz[(r0 + t)*(2*D_INNER) + D_INNER + d];
    float sz = z / (1.f + __expf(-z));
    y2b[base + (size_t)t*D_INNER] = f2bf((acc + xv*dp) * sz);
  }
}

// ---------------- K9: out = LN(q + attn) * g + b  -> fp32 -------------------------------
__global__ void k_ln(const float* __restrict__ attn,
                     const float* __restrict__ q,
                     const float* __restrict__ g,
                     const float* __restrict__ bb,
                     float* __restrict__ out) {
  const int r = blockIdx.x;
  const int t = threadIdx.x;
  float v0 = attn[(size_t)r*D_MODEL + t]       + q[(size_t)r*D_MODEL + t];
  float v1 = attn[(size_t)r*D_MODEL + 256 + t] + q[(size_t)r*D_MODEL + 256 + t];
  float s = v0 + v1, sq = v0*v0 + v1*v1;
  #pragma unroll
  for (int off = 32; off; off >>= 1) {
    s  += __shfl_xor(s, off);
    sq += __shfl_xor(sq, off);
  }
  __shared__ float ss[4], qq[4], stats[2];
  const int wid = t >> 6, lane = t & 63;
  if (lane == 0) { ss[wid] = s; qq[wid] = sq; }
  __syncthreads();
  if (t == 0) {
    float S = ss[0]+ss[1]+ss[2]+ss[3];
    float Q = qq[0]+qq[1]+qq[2]+qq[3];
    float mu = S * (1.f/D_MODEL);
    float var = Q * (1.f/D_MODEL) - mu*mu;
    stats[0] = mu; stats[1] = rsqrtf(var + 1e-5f);
  }
  __syncthreads();
  float mu = stats[0], rs = stats[1];
  out[(size_t)r*D_MODEL + t]       = (v0-mu)*rs*g[t]     + bb[t];
  out[(size_t)r*D_MODEL + 256 + t] = (v1-mu)*rs*g[256+t] + bb[256+t];
}

extern "C" void kernel_launch(void* const* d_in, const int* in_sizes, int n_in,
                              void* d_out, int out_size, void* d_ws, size_t ws_size,
                              hipStream_t stream) {
  (void)in_sizes; (void)n_in; (void)out_size; (void)ws_size;
  const float* q    = (const float*)d_in[0];
  const float* diff = (const float*)d_in[2];
  const float* aw   = (const float*)d_in[3];
  const float* ab   = (const float*)d_in[4];
  const float* inw  = (const float*)d_in[5];
  const float* cw   = (const float*)d_in[6];
  const float* cb   = (const float*)d_in[7];
  const float* xw   = (const float*)d_in[8];
  const float* dtw  = (const float*)d_in[9];
  const float* dtb  = (const float*)d_in[10];
  const float* alog = (const float*)d_in[11];
  const float* Dp   = (const float*)d_in[12];
  const float* outw = (const float*)d_in[13];
  const float* lng  = (const float*)d_in[14];
  const float* lnb  = (const float*)d_in[15];
  float* out = (float*)d_out;

  float* ws = (float*)d_ws;
  // fp32 region
  float* m      = ws;                                // 2048
  float* xz     = ws + 2048;                         // 8,388,608
  float* xc     = xz + (size_t)RR*2*D_INNER;         // 4,194,304
  float* xdb    = xc + (size_t)RR*D_INNER;           // 262,144
  float* aprod  = xdb + (size_t)RR*64;               // 2,097,152
  float* hstate = aprod + (size_t)BB*NC*D_INNER*16;  // 2,097,152
  float* attn   = aprod;                             // reuse (aprod dead after k_scan2)
  // bf16 region (shorts)
  short* amod  = (short*)(hstate + (size_t)BB*NC*D_INNER*16);  // 4096*512
  short* inwb  = amod + (size_t)RR*D_MODEL;                    // 2048*512
  short* outwb = inwb + (size_t)2*D_INNER*D_MODEL;             // 512*1024
  short* y2b   = outwb + (size_t)D_MODEL*D_INNER;              // 4096*1024

  k_ada<<<dim3(4,2), 256, 0, stream>>>(diff, aw, ab, m);
  k_cvtw<<<(2048*512 + 512*1024)/(256*4), 256, 0, stream>>>(inw, outw, inwb, outwb);
  k_amod<<<(RR*D_MODEL)/(256*4), 256, 0, stream>>>(q, m, amod);
  k_gemm_bf16<<<dim3((2*D_INNER)/64, RR/64), 256, 0, stream>>>(amod, inwb, xz, D_MODEL, 2*D_INNER);
  k_conv<<<(RR*D_INNER)/256, 256, 0, stream>>>(xz, cw, cb, xc);
  hipMemsetAsync(xdb, 0, (size_t)RR*64*sizeof(float), stream);
  k_xproj_t<<<dim3(8, RR/64), dim3(16,16), 0, stream>>>(xc, xw, xdb);
  k_scan1<<<dim3(D_INNER/256, NC, BB), 256, 0, stream>>>(xc, xdb, alog, dtw, dtb, aprod, hstate);
  k_scan2<<<(BB*D_INNER*16)/256, 256, 0, stream>>>(aprod, hstate);
  k_scan3<<<dim3(D_INNER/256, NC, BB), 256, 0, stream>>>(xc, xdb, alog, dtw, dtb, hstate, Dp, xz, y2b);
  k_gemm_bf16<<<dim3(D_MODEL/64, RR/64), 256, 0, stream>>>(y2b, outwb, attn, D_INNER, D_MODEL);
  k_ln<<<RR, 256, 0, stream>>>(attn, q, lng, lnb, out);
}

// Round 6
// 295.818 us; speedup vs baseline: 5.0904x; 1.0449x over previous
//
#include <hip/hip_runtime.h>
#include <hip/hip_bf16.h>

#define D_MODEL 512
#define D_INNER 1024
#define D_STATE 16
#define DT_RANK 32
#define BB 2
#define LL 2048
#define RR (BB*LL)   // 4096
#define NC 128       // chunks per sequence
#define CS 16        // chunk size (NC*CS == LL)

typedef __attribute__((ext_vector_type(8))) short short8;
typedef __attribute__((ext_vector_type(4))) short short4v;
typedef __attribute__((ext_vector_type(4))) float f32x4;

static __device__ __forceinline__ short f2bf(float f) {
  union { __hip_bfloat16 h; short s; } u;
  u.h = __float2bfloat16(f);
  return u.s;
}

// ---------------- K1: m = silu(diff) @ ada_w.T + ada_b  (m: [2][1024] fp32) ------------
__global__ void k_ada(const float* __restrict__ diff,
                      const float* __restrict__ aw,
                      const float* __restrict__ ab,
                      float* __restrict__ m) {
  __shared__ float sd[D_MODEL];
  const int b = blockIdx.y;
  const int t = threadIdx.x;
  for (int k = t; k < D_MODEL; k += 256) {
    float v = diff[b*D_MODEL + k];
    sd[k] = v / (1.f + __expf(-v));
  }
  __syncthreads();
  const int j = blockIdx.x*256 + t;  // 0..1023
  const float4* wr = reinterpret_cast<const float4*>(aw + (size_t)j*D_MODEL);
  float acc = ab[j];
  #pragma unroll 4
  for (int k4 = 0; k4 < D_MODEL/4; ++k4) {
    float4 wv = wr[k4];
    acc += sd[4*k4]*wv.x + sd[4*k4+1]*wv.y + sd[4*k4+2]*wv.z + sd[4*k4+3]*wv.w;
  }
  m[b*(2*D_MODEL) + j] = acc;
}

// ---------------- K1b: convert in_proj_w and out_proj_w to bf16 (once) ------------------
__global__ void k_cvtw(const float* __restrict__ inw,   // 2048*512
                       const float* __restrict__ outw,  // 512*1024
                       short* __restrict__ inwb,
                       short* __restrict__ outwb) {
  const int N1 = 2048*512, N2 = 512*1024;
  int gid = blockIdx.x*256 + threadIdx.x;
  const int idx = gid*4;
  if (idx < N1) {
    float4 v = *reinterpret_cast<const float4*>(inw + idx);
    short4v s = {f2bf(v.x), f2bf(v.y), f2bf(v.z), f2bf(v.w)};
    *reinterpret_cast<short4v*>(inwb + idx) = s;
  } else if (idx < N1 + N2) {
    float4 v = *reinterpret_cast<const float4*>(outw + (idx - N1));
    short4v s = {f2bf(v.x), f2bf(v.y), f2bf(v.z), f2bf(v.w)};
    *reinterpret_cast<short4v*>(outwb + (idx - N1)) = s;
  }
}

// ---------------- K1c: amod = bf16(q*(1+scale)+shift)   [4096][512] bf16 ----------------
__global__ void k_amod(const float* __restrict__ q,
                       const float* __restrict__ m,
                       short* __restrict__ amod) {
  const int gid = blockIdx.x*256 + threadIdx.x;   // over 4096*512/4
  const int idx = gid*4;
  const int r = idx >> 9, k = idx & 511;
  const float* mrow = m + (r >> 11)*(2*D_MODEL);
  float4 a = *reinterpret_cast<const float4*>(q + idx);
  float4 s = *reinterpret_cast<const float4*>(mrow + k);
  float4 h = *reinterpret_cast<const float4*>(mrow + D_MODEL + k);
  short4v o = {f2bf(a.x*(1.f+s.x)+h.x), f2bf(a.y*(1.f+s.y)+h.y),
               f2bf(a.z*(1.f+s.z)+h.z), f2bf(a.w*(1.f+s.w)+h.w)};
  *reinterpret_cast<short4v*>(amod + idx) = o;
}

// ---------------- unified bf16 MFMA GEMM: C[M][N] = A[M][K] x B[N][K]^T -----------------
__global__ void __launch_bounds__(256) k_gemm_bf16(
    const short* __restrict__ A,
    const short* __restrict__ B,
    float* __restrict__ C,
    int K, int ldc) {
  __shared__ short As[64][48];
  __shared__ short Bs[64][48];
  const int t = threadIdx.x;
  const int wave = t >> 6, lane = t & 63;
  const int quad = lane >> 4, l16 = lane & 15;
  const int row0 = blockIdx.y*64;
  const int col0 = blockIdx.x*64;
  const int tr = t >> 2;          // 0..63
  const int tk = (t & 3)*8;       // 0,8,16,24
  f32x4 acc[4] = {};
  for (int k0 = 0; k0 < K; k0 += 32) {
    *reinterpret_cast<short8*>(&As[tr][tk]) =
        *reinterpret_cast<const short8*>(A + (size_t)(row0+tr)*K + k0 + tk);
    *reinterpret_cast<short8*>(&Bs[tr][tk]) =
        *reinterpret_cast<const short8*>(B + (size_t)(col0+tr)*K + k0 + tk);
    __syncthreads();
    short8 af = *reinterpret_cast<const short8*>(&As[wave*16 + l16][quad*8]);
    #pragma unroll
    for (int nt = 0; nt < 4; ++nt) {
      short8 bf = *reinterpret_cast<const short8*>(&Bs[nt*16 + l16][quad*8]);
      acc[nt] = __builtin_amdgcn_mfma_f32_16x16x32_bf16(af, bf, acc[nt], 0, 0, 0);
    }
    __syncthreads();
  }
  #pragma unroll
  for (int nt = 0; nt < 4; ++nt)
    #pragma unroll
    for (int r = 0; r < 4; ++r)
      C[(size_t)(row0 + wave*16 + quad*4 + r)*ldc + col0 + nt*16 + l16] = acc[nt][r];
}

// ---------------- K3: xc = silu(causal_conv4(xm) + conv_b)   [4096][1024] fp32 ----------
__global__ void k_conv(const float* __restrict__ xz,
                       const float* __restrict__ cw,  // [1024][4]
                       const float* __restrict__ cb,
                       float* __restrict__ xc) {
  const int gid = blockIdx.x*256 + threadIdx.x;   // over 4096*1024
  const int d = gid & (D_INNER-1);
  const int r = gid >> 10;
  const int l = r & (LL-1);
  float4 cv = *reinterpret_cast<const float4*>(cw + (size_t)d*4);
  float wv[4] = {cv.x, cv.y, cv.z, cv.w};
  float acc = cb[d];
  #pragma unroll
  for (int k = 0; k < 4; ++k) {
    int ls = l + k - 3;
    if (ls >= 0) acc += xz[(size_t)(r + k - 3)*(2*D_INNER) + d] * wv[k];
  }
  xc[gid] = acc / (1.f + __expf(-acc));
}

// ---------------- K4: xdb += xc @ x_proj_w.T  (fp32, K-split x8, atomic accumulate) -----
__global__ void k_xproj_t(const float* __restrict__ xc,   // [4096][1024]
                          const float* __restrict__ xw,   // [64][1024]
                          float* __restrict__ xdb) {      // [4096][64] (pre-zeroed)
  __shared__ float As[16][68];
  __shared__ float Bs[16][68];
  const int tx = threadIdx.x, ty = threadIdx.y;
  const int t = ty*16 + tx;
  const int row0 = blockIdx.y*64;
  const int kbase = blockIdx.x*128;   // 8 chunks of 128
  float acc[4][4] = {};
  for (int k0 = kbase; k0 < kbase + 128; k0 += 16) {
    #pragma unroll
    for (int i = 0; i < 4; ++i) {
      int e = t + i*256;
      int kk = e & 15, rr = e >> 4;
      As[kk][rr] = xc[(size_t)(row0+rr)*D_INNER + k0+kk];
      Bs[kk][rr] = xw[(size_t)rr*D_INNER + k0+kk];
    }
    __syncthreads();
    #pragma unroll
    for (int kk = 0; kk < 16; ++kk) {
      float4 av = *reinterpret_cast<const float4*>(&As[kk][ty*4]);
      float4 bv = *reinterpret_cast<const float4*>(&Bs[kk][tx*4]);
      float a[4] = {av.x, av.y, av.z, av.w};
      float bq[4] = {bv.x, bv.y, bv.z, bv.w};
      #pragma unroll
      for (int i = 0; i < 4; ++i)
        #pragma unroll
        for (int j = 0; j < 4; ++j)
          acc[i][j] += a[i]*bq[j];
    }
    __syncthreads();
  }
  #pragma unroll
  for (int i = 0; i < 4; ++i)
    #pragma unroll
    for (int j = 0; j < 4; ++j)
      unsafeAtomicAdd(&xdb[(size_t)(row0+ty*4+i)*64 + tx*4 + j], acc[i][j]);
}

// ---------------- K6a: chunk-local scan + fused delta; outputs aprod/hstate -------------
__global__ void __launch_bounds__(256) k_scan1(
    const float* __restrict__ xc,
    const float* __restrict__ xdb,
    const float* __restrict__ alog,
    const float* __restrict__ dtw,   // [1024][32]
    const float* __restrict__ dtb,
    float* __restrict__ aprod,
    float* __restrict__ hstate) {
  const int d = blockIdx.x*256 + threadIdx.x;
  const int c = blockIdx.y;
  const int b = blockIdx.z;
  float A[D_STATE], ap[D_STATE], h[D_STATE], dwr[DT_RANK];
  const float4* dwp = reinterpret_cast<const float4*>(dtw + (size_t)d*DT_RANK);
  #pragma unroll
  for (int i = 0; i < 8; ++i) {
    float4 v = dwp[i];
    dwr[4*i]=v.x; dwr[4*i+1]=v.y; dwr[4*i+2]=v.z; dwr[4*i+3]=v.w;
  }
  const float dbv = dtb[d];
  const float4* alp = reinterpret_cast<const float4*>(alog + (size_t)d*D_STATE);
  #pragma unroll
  for (int i = 0; i < 4; ++i) {
    float4 av = alp[i];
    A[4*i+0] = -__expf(av.x); A[4*i+1] = -__expf(av.y);
    A[4*i+2] = -__expf(av.z); A[4*i+3] = -__expf(av.w);
  }
  #pragma unroll
  for (int n = 0; n < D_STATE; ++n) { ap[n] = 1.f; h[n] = 0.f; }
  const size_t base = ((size_t)b*LL + (size_t)c*CS)*D_INNER + d;
  const float* xrow = xdb + ((size_t)b*LL + (size_t)c*CS)*64;
  for (int t = 0; t < CS; ++t) {
    const float4* dtp = reinterpret_cast<const float4*>(xrow + t*64);
    float dacc = dbv;
    #pragma unroll
    for (int i = 0; i < 8; ++i) {
      float4 v = dtp[i];
      dacc += v.x*dwr[4*i] + v.y*dwr[4*i+1] + v.z*dwr[4*i+2] + v.w*dwr[4*i+3];
    }
    float dlt = (dacc > 20.f) ? dacc : __logf(1.f + __expf(dacc));
    float xv  = xc[base + (size_t)t*D_INNER];
    float dx = dlt * xv;
    const float4* bptr = reinterpret_cast<const float4*>(xrow + t*64 + 32);
    float Bv[D_STATE];
    #pragma unroll
    for (int i = 0; i < 4; ++i) {
      float4 bq = bptr[i];
      Bv[4*i+0]=bq.x; Bv[4*i+1]=bq.y; Bv[4*i+2]=bq.z; Bv[4*i+3]=bq.w;
    }
    #pragma unroll
    for (int n = 0; n < D_STATE; ++n) {
      float e = __expf(dlt*A[n]);
      ap[n] *= e;
      h[n] = e*h[n] + dx*Bv[n];
    }
  }
  const size_t sidx = (((size_t)b*NC + c)*D_INNER + d)*16;
  #pragma unroll
  for (int i = 0; i < 4; ++i) {
    *reinterpret_cast<float4*>(aprod + sidx + 4*i) =
        make_float4(ap[4*i], ap[4*i+1], ap[4*i+2], ap[4*i+3]);
    *reinterpret_cast<float4*>(hstate + sidx + 4*i) =
        make_float4(h[4*i], h[4*i+1], h[4*i+2], h[4*i+3]);
  }
}

// ---------------- K6b: combine chunk states; hstate[c] becomes INCOMING state -----------
__global__ void k_scan2(const float* __restrict__ aprod,
                        float* __restrict__ hstate) {
  const int gid = blockIdx.x*256 + threadIdx.x;   // over BB*D_INNER*16 = 32768
  const int b = gid >> 14;
  const int dn = gid & 16383;
  float h = 0.f;
  for (int c = 0; c < NC; ++c) {
    const size_t idx = ((size_t)(b*NC + c))*D_INNER*16 + dn;
    float a  = aprod[idx];
    float hl = hstate[idx];
    hstate[idx] = h;
    h = a*h + hl;
  }
}

// ---------------- K6c: seeded re-scan + fused delta + fused gate -> y2b (bf16) ----------
__global__ void __launch_bounds__(256) k_scan3(
    const float* __restrict__ xc,
    const float* __restrict__ xdb,
    const float* __restrict__ alog,
    const float* __restrict__ dtw,
    const float* __restrict__ dtb,
    const float* __restrict__ hstate,
    const float* __restrict__ Dp,
    const float* __restrict__ xz,    // read z at +D_INNER
    short* __restrict__ y2b) {       // [4096][1024] bf16
  const int d = blockIdx.x*256 + threadIdx.x;
  const int c = blockIdx.y;
  const int b = blockIdx.z;
  float A[D_STATE], h[D_STATE], dwr[DT_RANK];
  const float4* dwp = reinterpret_cast<const float4*>(dtw + (size_t)d*DT_RANK);
  #pragma unroll
  for (int i = 0; i < 8; ++i) {
    float4 v = dwp[i];
    dwr[4*i]=v.x; dwr[4*i+1]=v.y; dwr[4*i+2]=v.z; dwr[4*i+3]=v.w;
  }
  const float dbv = dtb[d];
  const float4* alp = reinterpret_cast<const float4*>(alog + (size_t)d*D_STATE);
  #pragma unroll
  for (int i = 0; i < 4; ++i) {
    float4 av = alp[i];
    A[4*i+0] = -__expf(av.x); A[4*i+1] = -__expf(av.y);
    A[4*i+2] = -__expf(av.z); A[4*i+3] = -__expf(av.w);
  }
  const size_t sidx = (((size_t)b*NC + c)*D_INNER + d)*16;
  #pragma unroll
  for (int i = 0; i < 4; ++i) {
    float4 hq = *reinterpret_cast<const float4*>(hstate + sidx + 4*i);
    h[4*i+0]=hq.x; h[4*i+1]=hq.y; h[4*i+2]=hq.z; h[4*i+3]=hq.w;
  }
  const float dp = Dp[d];
  const size_t r0 = (size_t)b*LL + (size_t)c*CS;
  const size_t base = r0*D_INNER + d;
  const float* xrow = xdb + r0*64;
  for (int t = 0; t < CS; ++t) {
    const float4* dtp = reinterpret_cast<const float4*>(xrow + t*64);
    float dacc = dbv;
    #pragma unroll
    for (int i = 0; i < 8; ++i) {
      float4 v = dtp[i];
      dacc += v.x*dwr[4*i] + v.y*dwr[4*i+1] + v.z*dwr[4*i+2] + v.w*dwr[4*i+3];
    }
    float dlt = (dacc > 20.f) ? dacc : __logf(1.f + __expf(dacc));
    float xv  = xc[base + (size_t)t*D_INNER];
    float dx = dlt * xv;
    const float4* bc = reinterpret_cast<const float4*>(xrow + t*64 + 32);
    float Bv[D_STATE], Cv[D_STATE];
    #pragma unroll
    for (int i = 0; i < 4; ++i) {
      float4 bq = bc[i], cq = bc[4+i];
      Bv[4*i+0]=bq.x; Bv[4*i+1]=bq.y; Bv[4*i+2]=bq.z; Bv[4*i+3]=bq.w;
      Cv[4*i+0]=cq.x; Cv[4*i+1]=cq.y; Cv[4*i+2]=cq.z; Cv[4*i+3]=cq.w;
    }
    float acc = 0.f;
    #pragma unroll
    for (int n = 0; n < D_STATE; ++n) {
      float e = __expf(dlt*A[n]);
      h[n] = e*h[n] + dx*Bv[n];
      acc += h[n]*Cv[n];
    }
    float z = xz[(r0 + t)*(2*D_INNER) + D_INNER + d];
    float sz = z / (1.f + __expf(-z));
    y2b[base + (size_t)t*D_INNER] = f2bf((acc + xv*dp) * sz);
  }
}

// ---------------- K9: out = LN(q + attn) * g + b  -> fp32 -------------------------------
__global__ void k_ln(const float* __restrict__ attn,
                     const float* __restrict__ q,
                     const float* __restrict__ g,
                     const float* __restrict__ bb,
                     float* __restrict__ out) {
  const int r = blockIdx.x;
  const int t = threadIdx.x;
  float v0 = attn[(size_t)r*D_MODEL + t]       + q[(size_t)r*D_MODEL + t];
  float v1 = attn[(size_t)r*D_MODEL + 256 + t] + q[(size_t)r*D_MODEL + 256 + t];
  float s = v0 + v1, sq = v0*v0 + v1*v1;
  #pragma unroll
  for (int off = 32; off; off >>= 1) {
    s  += __shfl_xor(s, off);
    sq += __shfl_xor(sq, off);
  }
  __shared__ float ss[4], qq[4], stats[2];
  const int wid = t >> 6, lane = t & 63;
  if (lane == 0) { ss[wid] = s; qq[wid] = sq; }
  __syncthreads();
  if (t == 0) {
    float S = ss[0]+ss[1]+ss[2]+ss[3];
    float Q = qq[0]+qq[1]+qq[2]+qq[3];
    float mu = S * (1.f/D_MODEL);
    float var = Q * (1.f/D_MODEL) - mu*mu;
    stats[0] = mu; stats[1] = rsqrtf(var + 1e-5f);
  }
  __syncthreads();
  float mu = stats[0], rs = stats[1];
  out[(size_t)r*D_MODEL + t]       = (v0-mu)*rs*g[t]     + bb[t];
  out[(size_t)r*D_MODEL + 256 + t] = (v1-mu)*rs*g[256+t] + bb[256+t];
}

extern "C" void kernel_launch(void* const* d_in, const int* in_sizes, int n_in,
                              void* d_out, int out_size, void* d_ws, size_t ws_size,
                              hipStream_t stream) {
  (void)in_sizes; (void)n_in; (void)out_size; (void)ws_size;
  const float* q    = (const float*)d_in[0];
  const float* diff = (const float*)d_in[2];
  const float* aw   = (const float*)d_in[3];
  const float* ab   = (const float*)d_in[4];
  const float* inw  = (const float*)d_in[5];
  const float* cw   = (const float*)d_in[6];
  const float* cb   = (const float*)d_in[7];
  const float* xw   = (const float*)d_in[8];
  const float* dtw  = (const float*)d_in[9];
  const float* dtb  = (const float*)d_in[10];
  const float* alog = (const float*)d_in[11];
  const float* Dp   = (const float*)d_in[12];
  const float* outw = (const float*)d_in[13];
  const float* lng  = (const float*)d_in[14];
  const float* lnb  = (const float*)d_in[15];
  float* out = (float*)d_out;

  float* ws = (float*)d_ws;
  // fp32 region
  float* m      = ws;                                // 2048
  float* xz     = ws + 2048;                         // 8,388,608
  float* xc     = xz + (size_t)RR*2*D_INNER;         // 4,194,304
  float* xdb    = xc + (size_t)RR*D_INNER;           // 262,144
  float* aprod  = xdb + (size_t)RR*64;               // 4,194,304 (NC=128)
  float* hstate = aprod + (size_t)BB*NC*D_INNER*16;  // 4,194,304
  float* attn   = aprod;                             // reuse (aprod dead after k_scan2)
  // bf16 region (shorts)
  short* amod  = (short*)(hstate + (size_t)BB*NC*D_INNER*16);  // 4096*512
  short* inwb  = amod + (size_t)RR*D_MODEL;                    // 2048*512
  short* outwb = inwb + (size_t)2*D_INNER*D_MODEL;             // 512*1024
  short* y2b   = outwb + (size_t)D_MODEL*D_INNER;              // 4096*1024

  k_ada<<<dim3(4,2), 256, 0, stream>>>(diff, aw, ab, m);
  k_cvtw<<<(2048*512 + 512*1024)/(256*4), 256, 0, stream>>>(inw, outw, inwb, outwb);
  k_amod<<<(RR*D_MODEL)/(256*4), 256, 0, stream>>>(q, m, amod);
  k_gemm_bf16<<<dim3((2*D_INNER)/64, RR/64), 256, 0, stream>>>(amod, inwb, xz, D_MODEL, 2*D_INNER);
  k_conv<<<(RR*D_INNER)/256, 256, 0, stream>>>(xz, cw, cb, xc);
  hipMemsetAsync(xdb, 0, (size_t)RR*64*sizeof(float), stream);
  k_xproj_t<<<dim3(8, RR/64), dim3(16,16), 0, stream>>>(xc, xw, xdb);
  k_scan1<<<dim3(D_INNER/256, NC, BB), 256, 0, stream>>>(xc, xdb, alog, dtw, dtb, aprod, hstate);
  k_scan2<<<(BB*D_INNER*16)/256, 256, 0, stream>>>(aprod, hstate);
  k_scan3<<<dim3(D_INNER/256, NC, BB), 256, 0, stream>>>(xc, xdb, alog, dtw, dtb, hstate, Dp, xz, y2b);
  k_gemm_bf16<<<dim3(D_MODEL/64, RR/64), 256, 0, stream>>>(y2b, outwb, attn, D_INNER, D_MODEL);
  k_ln<<<RR, 256, 0, stream>>>(attn, q, lng, lnb, out);
}

// Round 7
// 287.295 us; speedup vs baseline: 5.2414x; 1.0297x over previous
//
#include <hip/hip_runtime.h>
#include <hip/hip_bf16.h>

#define D_MODEL 512
#define D_INNER 1024
#define D_STATE 16
#define DT_RANK 32
#define BB 2
#define LL 2048
#define RR (BB*LL)   // 4096
#define NC 128       // chunks per sequence
#define CS 16        // chunk size (NC*CS == LL)

typedef __attribute__((ext_vector_type(8))) short short8;
typedef __attribute__((ext_vector_type(4))) short short4v;
typedef __attribute__((ext_vector_type(4))) float f32x4;

static __device__ __forceinline__ short f2bf(float f) {
  union { __hip_bfloat16 h; short s; } u;
  u.h = __float2bfloat16(f);
  return u.s;
}

// ---------------- K1: m = silu(diff) @ ada_w.T + ada_b  (m: [2][1024] fp32) ------------
__global__ void k_ada(const float* __restrict__ diff,
                      const float* __restrict__ aw,
                      const float* __restrict__ ab,
                      float* __restrict__ m) {
  __shared__ float sd[D_MODEL];
  const int b = blockIdx.y;
  const int t = threadIdx.x;
  for (int k = t; k < D_MODEL; k += 256) {
    float v = diff[b*D_MODEL + k];
    sd[k] = v / (1.f + __expf(-v));
  }
  __syncthreads();
  const int j = blockIdx.x*256 + t;  // 0..1023
  const float4* wr = reinterpret_cast<const float4*>(aw + (size_t)j*D_MODEL);
  float acc = ab[j];
  #pragma unroll 4
  for (int k4 = 0; k4 < D_MODEL/4; ++k4) {
    float4 wv = wr[k4];
    acc += sd[4*k4]*wv.x + sd[4*k4+1]*wv.y + sd[4*k4+2]*wv.z + sd[4*k4+3]*wv.w;
  }
  m[b*(2*D_MODEL) + j] = acc;
}

// ---------------- K1b: convert in_proj_w and out_proj_w to bf16 (once) ------------------
__global__ void k_cvtw(const float* __restrict__ inw,   // 2048*512
                       const float* __restrict__ outw,  // 512*1024
                       short* __restrict__ inwb,
                       short* __restrict__ outwb) {
  const int N1 = 2048*512, N2 = 512*1024;
  int gid = blockIdx.x*256 + threadIdx.x;
  const int idx = gid*4;
  if (idx < N1) {
    float4 v = *reinterpret_cast<const float4*>(inw + idx);
    short4v s = {f2bf(v.x), f2bf(v.y), f2bf(v.z), f2bf(v.w)};
    *reinterpret_cast<short4v*>(inwb + idx) = s;
  } else if (idx < N1 + N2) {
    float4 v = *reinterpret_cast<const float4*>(outw + (idx - N1));
    short4v s = {f2bf(v.x), f2bf(v.y), f2bf(v.z), f2bf(v.w)};
    *reinterpret_cast<short4v*>(outwb + (idx - N1)) = s;
  }
}

// ---------------- K1c: amod = bf16(q*(1+scale)+shift)   [4096][512] bf16 ----------------
__global__ void k_amod(const float* __restrict__ q,
                       const float* __restrict__ m,
                       short* __restrict__ amod) {
  const int gid = blockIdx.x*256 + threadIdx.x;   // over 4096*512/4
  const int idx = gid*4;
  const int r = idx >> 9, k = idx & 511;
  const float* mrow = m + (r >> 11)*(2*D_MODEL);
  float4 a = *reinterpret_cast<const float4*>(q + idx);
  float4 s = *reinterpret_cast<const float4*>(mrow + k);
  float4 h = *reinterpret_cast<const float4*>(mrow + D_MODEL + k);
  short4v o = {f2bf(a.x*(1.f+s.x)+h.x), f2bf(a.y*(1.f+s.y)+h.y),
               f2bf(a.z*(1.f+s.z)+h.z), f2bf(a.w*(1.f+s.w)+h.w)};
  *reinterpret_cast<short4v*>(amod + idx) = o;
}

// ---------------- unified bf16 MFMA GEMM: C[M][N] = A[M][K] x B[N][K]^T -----------------
__global__ void __launch_bounds__(256) k_gemm_bf16(
    const short* __restrict__ A,
    const short* __restrict__ B,
    float* __restrict__ C,
    int K, int ldc) {
  __shared__ short As[64][48];
  __shared__ short Bs[64][48];
  const int t = threadIdx.x;
  const int wave = t >> 6, lane = t & 63;
  const int quad = lane >> 4, l16 = lane & 15;
  const int row0 = blockIdx.y*64;
  const int col0 = blockIdx.x*64;
  const int tr = t >> 2;          // 0..63
  const int tk = (t & 3)*8;       // 0,8,16,24
  f32x4 acc[4] = {};
  for (int k0 = 0; k0 < K; k0 += 32) {
    *reinterpret_cast<short8*>(&As[tr][tk]) =
        *reinterpret_cast<const short8*>(A + (size_t)(row0+tr)*K + k0 + tk);
    *reinterpret_cast<short8*>(&Bs[tr][tk]) =
        *reinterpret_cast<const short8*>(B + (size_t)(col0+tr)*K + k0 + tk);
    __syncthreads();
    short8 af = *reinterpret_cast<const short8*>(&As[wave*16 + l16][quad*8]);
    #pragma unroll
    for (int nt = 0; nt < 4; ++nt) {
      short8 bf = *reinterpret_cast<const short8*>(&Bs[nt*16 + l16][quad*8]);
      acc[nt] = __builtin_amdgcn_mfma_f32_16x16x32_bf16(af, bf, acc[nt], 0, 0, 0);
    }
    __syncthreads();
  }
  #pragma unroll
  for (int nt = 0; nt < 4; ++nt)
    #pragma unroll
    for (int r = 0; r < 4; ++r)
      C[(size_t)(row0 + wave*16 + quad*4 + r)*ldc + col0 + nt*16 + l16] = acc[nt][r];
}

// ---------------- K3: xc = silu(causal_conv4(xm) + conv_b), float4 over d ---------------
__global__ void k_conv4(const float* __restrict__ xz,
                        const float* __restrict__ cw,  // [1024][4]
                        const float* __restrict__ cb,
                        float* __restrict__ xc) {
  const int gid = blockIdx.x*256 + threadIdx.x;   // over 4096*256
  const int d4 = (gid & 255)*4;
  const int r = gid >> 8;
  const int l = r & (LL-1);
  float4 w0 = *reinterpret_cast<const float4*>(cw + (size_t)(d4+0)*4);
  float4 w1 = *reinterpret_cast<const float4*>(cw + (size_t)(d4+1)*4);
  float4 w2 = *reinterpret_cast<const float4*>(cw + (size_t)(d4+2)*4);
  float4 w3 = *reinterpret_cast<const float4*>(cw + (size_t)(d4+3)*4);
  float4 res = *reinterpret_cast<const float4*>(cb + d4);
  #pragma unroll
  for (int k = 0; k < 4; ++k) {
    int ls = l + k - 3;
    if (ls >= 0) {
      float4 xv = *reinterpret_cast<const float4*>(xz + (size_t)(r + k - 3)*(2*D_INNER) + d4);
      float wk0 = (&w0.x)[k], wk1 = (&w1.x)[k], wk2 = (&w2.x)[k], wk3 = (&w3.x)[k];
      res.x += xv.x*wk0; res.y += xv.y*wk1; res.z += xv.z*wk2; res.w += xv.w*wk3;
    }
  }
  res.x = res.x / (1.f + __expf(-res.x));
  res.y = res.y / (1.f + __expf(-res.y));
  res.z = res.z / (1.f + __expf(-res.z));
  res.w = res.w / (1.f + __expf(-res.w));
  *reinterpret_cast<float4*>(xc + (size_t)r*D_INNER + d4) = res;
}

// ---------------- K4: xdb += xc @ x_proj_w.T  (fp32, K-split x8, atomic accumulate) -----
__global__ void k_xproj_t(const float* __restrict__ xc,   // [4096][1024]
                          const float* __restrict__ xw,   // [64][1024]
                          float* __restrict__ xdb) {      // [4096][64] (pre-zeroed)
  __shared__ float As[16][68];
  __shared__ float Bs[16][68];
  const int tx = threadIdx.x, ty = threadIdx.y;
  const int t = ty*16 + tx;
  const int row0 = blockIdx.y*64;
  const int kbase = blockIdx.x*128;   // 8 chunks of 128
  float acc[4][4] = {};
  for (int k0 = kbase; k0 < kbase + 128; k0 += 16) {
    #pragma unroll
    for (int i = 0; i < 4; ++i) {
      int e = t + i*256;
      int kk = e & 15, rr = e >> 4;
      As[kk][rr] = xc[(size_t)(row0+rr)*D_INNER + k0+kk];
      Bs[kk][rr] = xw[(size_t)rr*D_INNER + k0+kk];
    }
    __syncthreads();
    #pragma unroll
    for (int kk = 0; kk < 16; ++kk) {
      float4 av = *reinterpret_cast<const float4*>(&As[kk][ty*4]);
      float4 bv = *reinterpret_cast<const float4*>(&Bs[kk][tx*4]);
      float a[4] = {av.x, av.y, av.z, av.w};
      float bq[4] = {bv.x, bv.y, bv.z, bv.w};
      #pragma unroll
      for (int i = 0; i < 4; ++i)
        #pragma unroll
        for (int j = 0; j < 4; ++j)
          acc[i][j] += a[i]*bq[j];
    }
    __syncthreads();
  }
  #pragma unroll
  for (int i = 0; i < 4; ++i)
    #pragma unroll
    for (int j = 0; j < 4; ++j)
      unsafeAtomicAdd(&xdb[(size_t)(row0+ty*4+i)*64 + tx*4 + j], acc[i][j]);
}

// ---------------- K5: delta = softplus(xdb[:, :32] @ dtw.T + dtb)  [4096][1024] ---------
__global__ void __launch_bounds__(256) k_deltaf(
    const float* __restrict__ xdb,   // [4096][64]
    const float* __restrict__ dtw,   // [1024][32]
    const float* __restrict__ dtb,
    float* __restrict__ delta) {     // [4096][1024]
  const int d = blockIdx.x*256 + threadIdx.x;
  const int r0 = blockIdx.y*16;
  float dwr[DT_RANK];
  const float4* dwp = reinterpret_cast<const float4*>(dtw + (size_t)d*DT_RANK);
  #pragma unroll
  for (int i = 0; i < 8; ++i) {
    float4 v = dwp[i];
    dwr[4*i]=v.x; dwr[4*i+1]=v.y; dwr[4*i+2]=v.z; dwr[4*i+3]=v.w;
  }
  const float dbv = dtb[d];
  for (int r = r0; r < r0 + 16; ++r) {
    const float4* xr = reinterpret_cast<const float4*>(xdb + (size_t)r*64);
    float acc = dbv;
    #pragma unroll
    for (int i = 0; i < 8; ++i) {
      float4 v = xr[i];
      acc += v.x*dwr[4*i] + v.y*dwr[4*i+1] + v.z*dwr[4*i+2] + v.w*dwr[4*i+3];
    }
    delta[(size_t)r*D_INNER + d] = (acc > 20.f) ? acc : __logf(1.f + __expf(acc));
  }
}

// ---------------- K6a: chunk-local scan; LDS-staged B; states in [b][c][n][d] -----------
__global__ void __launch_bounds__(256) k_scan1(
    const float* __restrict__ delta,
    const float* __restrict__ xc,
    const float* __restrict__ xdb,
    const float* __restrict__ alog,
    float* __restrict__ aprod,
    float* __restrict__ hstate) {
  __shared__ float sx[CS*64];
  const int tid = threadIdx.x;
  const int d = blockIdx.x*256 + tid;
  const int c = blockIdx.y;
  const int b = blockIdx.z;
  const float* xrow = xdb + ((size_t)b*LL + (size_t)c*CS)*64;
  *reinterpret_cast<float4*>(&sx[tid*4]) = *reinterpret_cast<const float4*>(xrow + tid*4);
  float A[D_STATE], ap[D_STATE], h[D_STATE];
  const float4* alp = reinterpret_cast<const float4*>(alog + (size_t)d*D_STATE);
  #pragma unroll
  for (int i = 0; i < 4; ++i) {
    float4 av = alp[i];
    A[4*i+0] = -__expf(av.x); A[4*i+1] = -__expf(av.y);
    A[4*i+2] = -__expf(av.z); A[4*i+3] = -__expf(av.w);
  }
  #pragma unroll
  for (int n = 0; n < D_STATE; ++n) { ap[n] = 1.f; h[n] = 0.f; }
  __syncthreads();
  const size_t base = ((size_t)b*LL + (size_t)c*CS)*D_INNER + d;
  for (int t = 0; t < CS; ++t) {
    float dlt = delta[base + (size_t)t*D_INNER];
    float xv  = xc[base + (size_t)t*D_INNER];
    float dx = dlt * xv;
    float Bv[D_STATE];
    #pragma unroll
    for (int i = 0; i < 4; ++i) {
      float4 bq = *reinterpret_cast<const float4*>(&sx[t*64 + 32 + 4*i]);
      Bv[4*i+0]=bq.x; Bv[4*i+1]=bq.y; Bv[4*i+2]=bq.z; Bv[4*i+3]=bq.w;
    }
    #pragma unroll
    for (int n = 0; n < D_STATE; ++n) {
      float e = __expf(dlt*A[n]);
      ap[n] *= e;
      h[n] = e*h[n] + dx*Bv[n];
    }
  }
  const size_t s0 = (((size_t)b*NC + c)*D_STATE)*D_INNER + d;
  #pragma unroll
  for (int n = 0; n < D_STATE; ++n) {
    aprod[s0 + (size_t)n*D_INNER]  = ap[n];
    hstate[s0 + (size_t)n*D_INNER] = h[n];
  }
}

// ---------------- K6b: combine chunk states ([b][c][n][d] layout) -----------------------
__global__ void k_scan2(const float* __restrict__ aprod,
                        float* __restrict__ hstate) {
  const int gid = blockIdx.x*256 + threadIdx.x;   // over BB*16*D_INNER = 32768
  const int b = gid >> 14;
  const int nd = gid & 16383;
  float h = 0.f;
  for (int c = 0; c < NC; ++c) {
    const size_t idx = (((size_t)b*NC + c)*D_STATE)*D_INNER + nd;
    float a  = aprod[idx];
    float hl = hstate[idx];
    hstate[idx] = h;
    h = a*h + hl;
  }
}

// ---------------- K6c: seeded re-scan + fused gate -> y2b (bf16) ------------------------
__global__ void __launch_bounds__(256) k_scan3(
    const float* __restrict__ delta,
    const float* __restrict__ xc,
    const float* __restrict__ xdb,
    const float* __restrict__ alog,
    const float* __restrict__ hstate,
    const float* __restrict__ Dp,
    const float* __restrict__ xz,    // read z at +D_INNER
    short* __restrict__ y2b) {       // [4096][1024] bf16
  __shared__ float sx[CS*64];
  const int tid = threadIdx.x;
  const int d = blockIdx.x*256 + tid;
  const int c = blockIdx.y;
  const int b = blockIdx.z;
  const float* xrow = xdb + ((size_t)b*LL + (size_t)c*CS)*64;
  *reinterpret_cast<float4*>(&sx[tid*4]) = *reinterpret_cast<const float4*>(xrow + tid*4);
  float A[D_STATE], h[D_STATE];
  const float4* alp = reinterpret_cast<const float4*>(alog + (size_t)d*D_STATE);
  #pragma unroll
  for (int i = 0; i < 4; ++i) {
    float4 av = alp[i];
    A[4*i+0] = -__expf(av.x); A[4*i+1] = -__expf(av.y);
    A[4*i+2] = -__expf(av.z); A[4*i+3] = -__expf(av.w);
  }
  const size_t s0 = (((size_t)b*NC + c)*D_STATE)*D_INNER + d;
  #pragma unroll
  for (int n = 0; n < D_STATE; ++n)
    h[n] = hstate[s0 + (size_t)n*D_INNER];
  const float dp = Dp[d];
  __syncthreads();
  const size_t r0 = (size_t)b*LL + (size_t)c*CS;
  const size_t base = r0*D_INNER + d;
  for (int t = 0; t < CS; ++t) {
    float dlt = delta[base + (size_t)t*D_INNER];
    float xv  = xc[base + (size_t)t*D_INNER];
    float dx = dlt * xv;
    float Bv[D_STATE], Cv[D_STATE];
    #pragma unroll
    for (int i = 0; i < 4; ++i) {
      float4 bq = *reinterpret_cast<const float4*>(&sx[t*64 + 32 + 4*i]);
      float4 cq = *reinterpret_cast<const float4*>(&sx[t*64 + 48 + 4*i]);
      Bv[4*i+0]=bq.x; Bv[4*i+1]=bq.y; Bv[4*i+2]=bq.z; Bv[4*i+3]=bq.w;
      Cv[4*i+0]=cq.x; Cv[4*i+1]=cq.y; Cv[4*i+2]=cq.z; Cv[4*i+3]=cq.w;
    }
    float acc = 0.f;
    #pragma unroll
    for (int n = 0; n < D_STATE; ++n) {
      float e = __expf(dlt*A[n]);
      h[n] = e*h[n] + dx*Bv[n];
      acc += h[n]*Cv[n];
    }
    float z = xz[(r0 + t)*(2*D_INNER) + D_INNER + d];
    float sz = z / (1.f + __expf(-z));
    y2b[base + (size_t)t*D_INNER] = f2bf((acc + xv*dp) * sz);
  }
}

// ---------------- K9: out = LN(q + attn) * g + b  -> fp32 -------------------------------
__global__ void k_ln(const float* __restrict__ attn,
                     const float* __restrict__ q,
                     const float* __restrict__ g,
                     const float* __restrict__ bb,
                     float* __restrict__ out) {
  const int r = blockIdx.x;
  const int t = threadIdx.x;
  float v0 = attn[(size_t)r*D_MODEL + t]       + q[(size_t)r*D_MODEL + t];
  float v1 = attn[(size_t)r*D_MODEL + 256 + t] + q[(size_t)r*D_MODEL + 256 + t];
  float s = v0 + v1, sq = v0*v0 + v1*v1;
  #pragma unroll
  for (int off = 32; off; off >>= 1) {
    s  += __shfl_xor(s, off);
    sq += __shfl_xor(sq, off);
  }
  __shared__ float ss[4], qq[4], stats[2];
  const int wid = t >> 6, lane = t & 63;
  if (lane == 0) { ss[wid] = s; qq[wid] = sq; }
  __syncthreads();
  if (t == 0) {
    float S = ss[0]+ss[1]+ss[2]+ss[3];
    float Q = qq[0]+qq[1]+qq[2]+qq[3];
    float mu = S * (1.f/D_MODEL);
    float var = Q * (1.f/D_MODEL) - mu*mu;
    stats[0] = mu; stats[1] = rsqrtf(var + 1e-5f);
  }
  __syncthreads();
  float mu = stats[0], rs = stats[1];
  out[(size_t)r*D_MODEL + t]       = (v0-mu)*rs*g[t]     + bb[t];
  out[(size_t)r*D_MODEL + 256 + t] = (v1-mu)*rs*g[256+t] + bb[256+t];
}

extern "C" void kernel_launch(void* const* d_in, const int* in_sizes, int n_in,
                              void* d_out, int out_size, void* d_ws, size_t ws_size,
                              hipStream_t stream) {
  (void)in_sizes; (void)n_in; (void)out_size; (void)ws_size;
  const float* q    = (const float*)d_in[0];
  const float* diff = (const float*)d_in[2];
  const float* aw   = (const float*)d_in[3];
  const float* ab   = (const float*)d_in[4];
  const float* inw  = (const float*)d_in[5];
  const float* cw   = (const float*)d_in[6];
  const float* cb   = (const float*)d_in[7];
  const float* xw   = (const float*)d_in[8];
  const float* dtw  = (const float*)d_in[9];
  const float* dtb  = (const float*)d_in[10];
  const float* alog = (const float*)d_in[11];
  const float* Dp   = (const float*)d_in[12];
  const float* outw = (const float*)d_in[13];
  const float* lng  = (const float*)d_in[14];
  const float* lnb  = (const float*)d_in[15];
  float* out = (float*)d_out;

  float* ws = (float*)d_ws;
  // fp32 region
  float* m      = ws;                                // 2048
  float* xz     = ws + 2048;                         // 8,388,608
  float* xc     = xz + (size_t)RR*2*D_INNER;         // 4,194,304
  float* xdb    = xc + (size_t)RR*D_INNER;           // 262,144
  float* aprod  = xdb + (size_t)RR*64;               // 4,194,304
  float* hstate = aprod + (size_t)BB*NC*D_INNER*16;  // 4,194,304
  float* delta  = hstate + (size_t)BB*NC*D_INNER*16; // 4,194,304
  float* attn   = aprod;                             // reuse (aprod dead after k_scan2)
  // bf16 region (shorts)
  short* amod  = (short*)(delta + (size_t)RR*D_INNER);  // 4096*512
  short* inwb  = amod + (size_t)RR*D_MODEL;             // 2048*512
  short* outwb = inwb + (size_t)2*D_INNER*D_MODEL;      // 512*1024
  short* y2b   = outwb + (size_t)D_MODEL*D_INNER;       // 4096*1024

  k_ada<<<dim3(4,2), 256, 0, stream>>>(diff, aw, ab, m);
  k_cvtw<<<(2048*512 + 512*1024)/(256*4), 256, 0, stream>>>(inw, outw, inwb, outwb);
  k_amod<<<(RR*D_MODEL)/(256*4), 256, 0, stream>>>(q, m, amod);
  k_gemm_bf16<<<dim3((2*D_INNER)/64, RR/64), 256, 0, stream>>>(amod, inwb, xz, D_MODEL, 2*D_INNER);
  k_conv4<<<(RR*D_INNER/4)/256, 256, 0, stream>>>(xz, cw, cb, xc);
  hipMemsetAsync(xdb, 0, (size_t)RR*64*sizeof(float), stream);
  k_xproj_t<<<dim3(8, RR/64), dim3(16,16), 0, stream>>>(xc, xw, xdb);
  k_deltaf<<<dim3(D_INNER/256, RR/16), 256, 0, stream>>>(xdb, dtw, dtb, delta);
  k_scan1<<<dim3(D_INNER/256, NC, BB), 256, 0, stream>>>(delta, xc, xdb, alog, aprod, hstate);
  k_scan2<<<(BB*D_INNER*16)/256, 256, 0, stream>>>(aprod, hstate);
  k_scan3<<<dim3(D_INNER/256, NC, BB), 256, 0, stream>>>(delta, xc, xdb, alog, hstate, Dp, xz, y2b);
  k_gemm_bf16<<<dim3(D_MODEL/64, RR/64), 256, 0, stream>>>(y2b, outwb, attn, D_INNER, D_MODEL);
  k_ln<<<RR, 256, 0, stream>>>(attn, q, lng, lnb, out);
}